// Round 7
// baseline (495.540 us; speedup 1.0000x reference)
//
#include <hip/hip_runtime.h>
#include <hip/hip_bf16.h>
#include <hip/hip_fp8.h>
#include <cstdint>
#include <cstddef>

// Problem: B=4, S=4096, D=256 two-layer full attention + VAE head. fp32 I/O.
// Strategy: MX-scaled fp8 MFMA flash attention (v15: v12 skeleton, V in regs
// single-buffered, K 3-ring, compiler-counted vmcnt); bf16 MFMA GEMMs.

#define S_LEN 4096
#define DMODEL 256
#define NBATCH 4

typedef __bf16 bf16;
typedef __bf16 bf16x8 __attribute__((ext_vector_type(8)));
typedef float f32x4 __attribute__((ext_vector_type(4)));
typedef float f32x16 __attribute__((ext_vector_type(16)));
typedef int i32x4 __attribute__((ext_vector_type(4)));
typedef int i32x8 __attribute__((ext_vector_type(8)));
typedef unsigned char u8;
typedef unsigned int u32;

__device__ __forceinline__ f32x4 mfma16(bf16x8 a, bf16x8 b, f32x4 c) {
  return __builtin_amdgcn_mfma_f32_16x16x32_bf16(a, b, c, 0, 0, 0);
}
// MX-scaled fp8 MFMA, K=64, unit scales (e8m0 0x7F = 2^0): plain fp8 matmul at 2x rate.
__device__ __forceinline__ f32x16 mfma_mx(i32x8 a, i32x8 b, f32x16 c) {
  return __builtin_amdgcn_mfma_scale_f32_32x32x64_f8f6f4(
      a, b, c, 0, 0, 0, 0x7F7F7F7F, 0, 0x7F7F7F7F);
}
__device__ __forceinline__ i32x8 cat8(i32x4 a, i32x4 b) {
  return __builtin_shufflevector(a, b, 0, 1, 2, 3, 4, 5, 6, 7);
}

// Async global->LDS, 16B per lane. LDS dest: wave-uniform base + lane*16.
__device__ __forceinline__ void async16(const void* g, void* lds) {
  __builtin_amdgcn_global_load_lds(
      (const __attribute__((address_space(1))) unsigned int*)g,
      (__attribute__((address_space(3))) unsigned int*)lds, 16, 0, 0);
}

__device__ __forceinline__ unsigned short f2bfbits(float f) {
  return __builtin_bit_cast(unsigned short, (bf16)f);
}
__device__ __forceinline__ u8 f2fp8(float f) {
  __hip_fp8_e4m3 t(f);  // OCP e4m3fn
  return *(u8*)&t;
}
// half-split column permutation over 256-wide d for K=64 scaled MFMA:
// k = b2*64 + h*32 + m -> position h*128 + b2*32 + m.
__device__ __forceinline__ int permc(int v) {
  return (((v >> 5) & 1) << 7) + (((v >> 6) & 3) << 5) + (v & 31);
}
// same over a 128-wide dim: k = b2*64 + h*32 + m -> h*64 + b2*32 + m.
__device__ __forceinline__ int permc128(int v) {
  return (((v >> 5) & 1) << 6) + (((v >> 6) & 1) << 5) + (v & 31);
}

// ---------------- cast kernel (x + 8 weight mats in one launch) ----------------
struct WPtrs { const float* p[8]; };

__global__ void cast_all_kernel(const f32x4* __restrict__ x, WPtrs wp,
                                ushort4* __restrict__ x16, ushort4* __restrict__ w16) {
  int bx = blockIdx.x, t = threadIdx.x;
  const f32x4* src;
  ushort4* dst;
  if (bx < 4096) {
    src = x + (size_t)bx * 256 + t;
    dst = x16 + (size_t)bx * 256 + t;
  } else {
    int r = bx - 4096;
    int m = r >> 6;
    int i = (r & 63) * 256 + t;
    src = (const f32x4*)wp.p[m] + i;
    dst = w16 + (size_t)m * 16384 + i;
  }
  f32x4 v = *src;
  ushort4 o;
  o.x = f2bfbits(v[0]); o.y = f2bfbits(v[1]); o.z = f2bfbits(v[2]); o.w = f2bfbits(v[3]);
  *dst = o;
}

// ---------------- GEMM: out[m][n] = sum_k A[m][k]*W[n][k] + bias[n] ----------------
// z=0: Q fp8 (plain [M][256]); z=1: K fp8 (permc cols, [M][256]);
// z=2: V fp8 transposed tile-major [B][S/128][256 d][128 kv permc128].
struct GemmIO {
  const float* bias[3];
  void* out[3];
};

__global__ __launch_bounds__(256, 3) void gemm_qkv_kernel(const bf16* __restrict__ A,
                                                          const bf16* __restrict__ Wb,
                                                          GemmIO io) {
  __shared__ bf16 ldsA[128 * 64];
  __shared__ bf16 ldsB[128 * 64];
  const int t = threadIdx.x;
  const int m0 = blockIdx.x * 128;
  const int n0 = blockIdx.y * 128;
  const bf16* W = Wb + (size_t)blockIdx.z * 65536;
  const int w = t >> 6, l = t & 63, lm = l & 15, q = l >> 4;
  const int wr = (w >> 1) * 64, wc = (w & 1) * 64;

  f32x4 acc[4][4] = {};
#pragma unroll 1
  for (int it = 0; it < 4; ++it) {
    const int k0 = it * 64;
#pragma unroll
    for (int c = 0; c < 4; ++c) {
      int i = c * 256 + t;
      int r = i >> 3, c8 = (i & 7) ^ (r & 7);
      async16(A + (size_t)(m0 + r) * 256 + k0 + c8 * 8, &ldsA[i * 8]);
    }
#pragma unroll
    for (int c = 0; c < 4; ++c) {
      int i = c * 256 + t;
      int r = i >> 3, c8 = (i & 7) ^ (r & 7);
      async16(W + (size_t)(n0 + r) * 256 + k0 + c8 * 8, &ldsB[i * 8]);
    }
    __syncthreads();
#pragma unroll
    for (int ks = 0; ks < 2; ++ks) {
      bf16x8 af[4], bfr[4];
#pragma unroll
      for (int i = 0; i < 4; ++i) {
        int ra = wr + i * 16 + lm;
        af[i] = *(const bf16x8*)&ldsA[ra * 64 + ((((ks << 2) + q) ^ (ra & 7)) << 3)];
        int rb = wc + i * 16 + lm;
        bfr[i] = *(const bf16x8*)&ldsB[rb * 64 + ((((ks << 2) + q) ^ (rb & 7)) << 3)];
      }
#pragma unroll
      for (int i = 0; i < 4; ++i)
#pragma unroll
        for (int jj = 0; jj < 4; ++jj) acc[i][jj] = mfma16(af[i], bfr[jj], acc[i][jj]);
    }
    __syncthreads();
  }
  const float* bias = io.bias[blockIdx.z];
  if (blockIdx.z == 2) {
    // V: write fp8 V^T tile-major directly (fused transpose), kv permc128 per 128.
    u8* out = (u8*)io.out[2];
#pragma unroll
    for (int jj = 0; jj < 4; ++jj) {
      int col = n0 + wc + jj * 16 + lm;
      float bv = bias[col];
#pragma unroll
      for (int i = 0; i < 4; ++i) {
        int row = m0 + wr + i * 16 + q * 4;
#pragma unroll
        for (int r = 0; r < 4; ++r) {
          int rg = row + r;
          int bb = rg >> 12, s = rg & 4095;
          out[(((size_t)(bb * 32 + (s >> 7)) * 256 + col) << 7) + permc128(s & 127)] =
              f2fp8(acc[i][jj][r] + bv);
        }
      }
    }
  } else {
    u8* out = (u8*)io.out[blockIdx.z];
#pragma unroll
    for (int jj = 0; jj < 4; ++jj) {
      int col = n0 + wc + jj * 16 + lm;
      int scol = (blockIdx.z == 1) ? permc(col) : col;  // K gets half-split cols
      float bv = bias[col];
#pragma unroll
      for (int i = 0; i < 4; ++i) {
        int row = m0 + wr + i * 16 + q * 4;
#pragma unroll
        for (int r = 0; r < 4; ++r)
          out[(size_t)(row + r) * 256 + scol] = f2fp8(acc[i][jj][r] + bv);
      }
    }
  }
}

// mu/lv GEMM (fp32 out) — same structure.
__global__ __launch_bounds__(256, 3) void gemm_f_kernel(const bf16* __restrict__ A,
                                                        const bf16* __restrict__ Wb, GemmIO io) {
  __shared__ bf16 ldsA[128 * 64];
  __shared__ bf16 ldsB[128 * 64];
  const int t = threadIdx.x;
  const int m0 = blockIdx.x * 128;
  const int n0 = blockIdx.y * 128;
  const bf16* W = Wb + (size_t)blockIdx.z * 65536;
  const int w = t >> 6, l = t & 63, lm = l & 15, q = l >> 4;
  const int wr = (w >> 1) * 64, wc = (w & 1) * 64;

  f32x4 acc[4][4] = {};
#pragma unroll 1
  for (int it = 0; it < 4; ++it) {
    const int k0 = it * 64;
#pragma unroll
    for (int c = 0; c < 4; ++c) {
      int i = c * 256 + t;
      int r = i >> 3, c8 = (i & 7) ^ (r & 7);
      async16(A + (size_t)(m0 + r) * 256 + k0 + c8 * 8, &ldsA[i * 8]);
    }
#pragma unroll
    for (int c = 0; c < 4; ++c) {
      int i = c * 256 + t;
      int r = i >> 3, c8 = (i & 7) ^ (r & 7);
      async16(W + (size_t)(n0 + r) * 256 + k0 + c8 * 8, &ldsB[i * 8]);
    }
    __syncthreads();
#pragma unroll
    for (int ks = 0; ks < 2; ++ks) {
      bf16x8 af[4], bfr[4];
#pragma unroll
      for (int i = 0; i < 4; ++i) {
        int ra = wr + i * 16 + lm;
        af[i] = *(const bf16x8*)&ldsA[ra * 64 + ((((ks << 2) + q) ^ (ra & 7)) << 3)];
        int rb = wc + i * 16 + lm;
        bfr[i] = *(const bf16x8*)&ldsB[rb * 64 + ((((ks << 2) + q) ^ (rb & 7)) << 3)];
      }
#pragma unroll
      for (int i = 0; i < 4; ++i)
#pragma unroll
        for (int jj = 0; jj < 4; ++jj) acc[i][jj] = mfma16(af[i], bfr[jj], acc[i][jj]);
    }
    __syncthreads();
  }
  const float* bias = io.bias[blockIdx.z];
  float* out = (float*)io.out[blockIdx.z];
#pragma unroll
  for (int jj = 0; jj < 4; ++jj) {
    int col = n0 + wc + jj * 16 + lm;
    float bv = bias[col];
#pragma unroll
    for (int i = 0; i < 4; ++i) {
      int row = m0 + wr + i * 16 + q * 4;
#pragma unroll
      for (int r = 0; r < 4; ++r)
        out[(size_t)(row + r) * 256 + col] = acc[i][jj][r] + bv;
    }
  }
}

// ---------------- flash attention v15 ----------------
// 256 blocks (1/CU), 1024 threads = 16 waves. BM=64 Q rows, KV tile 128, 32 iters.
// Waves 0-7 = producers (qg=w&1, ks=w>>1): QK S^T strip mfma_mx(A=K_lds[j%3],
// B=Q_regs) k=256 chained into one f32x16; softmax in 4-reg groups; P ->
// ldsP[j&1] (permc128 kv, chunk^q swizzle); lgkmcnt(0) before barrier.
// Waves 8-15 = consumers (cqg=cw&1, dpair=cw>>1): STAGE K(j+2) -> ring slot
// (j+2)%3 (4 async16/lane); PV(j-1) = mfma_mx(A=P_lds, B=vA) k=128 into o0/o1;
// then CONSV(j) global->vA (single reg buffer; WAR after MFMA issue is safe).
// No manual vmcnt: the compiler's RAW wait before PV's MFMAs retires (in-order)
// iter j-1's CONSV and with it all older K staging -> K(j+1) ready pre-barrier.
// One s_barrier per iteration. Register diet keeps wave <=128 VGPR (4 w/SIMD).
__global__ __launch_bounds__(1024, 4) void flash_kernel(const u8* __restrict__ Q,
                                                        const u8* __restrict__ K,
                                                        const u8* __restrict__ Vt,
                                                        bf16* __restrict__ O) {
  __shared__ __align__(16) u8 ldsK[3][32768];         // 96KB: 3-slot K ring
  __shared__ __align__(16) u8 ldsP[2][2 * 32 * 128];  // 16KB: P double buffer
  __shared__ float lb[64];

  const int id = blockIdx.x;
  const int xcd = id & 7;
  const int b = xcd >> 1;
  const int qt = (id >> 3) + ((xcd & 1) << 5);  // 0..63

  const u8* Qb = Q + (size_t)b * S_LEN * 256;
  const u8* Kb = K + (size_t)b * S_LEN * 256;
  const u8* Vb = Vt + (size_t)b * 1048576;  // [32 tiles][256 d][128 kv]
  bf16* Ob = O + (size_t)b * S_LEN * 256;

  const int t = threadIdx.x, w = t >> 6, lane = t & 63;
  const int m31 = lane & 31, kh = lane >> 5;
  const bool prod = (w < 8);
  const float CL2 = 0.09016844005556021f;  // log2(e)/sqrt(D)

  if (t < 64) lb[t] = 0.f;

  // ---- producer setup (waves 0-7) ----
  const int qg = w & 1, ks = (w >> 1) & 3;
  const int kn = ks * 32 + m31;  // kv row in K tile
  const int kx = kn & 7;
  const int px = m31 & 7;
  i32x8 qf[4];
  if (prod) {
    const u8* qrow = Qb + (size_t)(qt * 64 + qg * 32 + m31) * 256 + kh * 32;
#pragma unroll
    for (int b2 = 0; b2 < 4; ++b2) qf[b2] = *(const i32x8*)(qrow + b2 * 64);
  }
  float l_w = 0.f;

  // ---- consumer setup (waves 8-15) ----
  const int cw = w - 8;
  const int cqg = cw & 1, dpair = cw >> 1;  // dpair 0..3
  const int vd0 = dpair * 64 + m31;         // V^T d-row
  const int ct = (t - 512) & 511;           // consumer linear id 0..511
  f32x16 o0 = {}, o1 = {};
  i32x4 vA[8];

  auto STAGE = [&](int m) {  // consumers: stage K tile m into ring slot m%3
    const u8* kg = Kb + (size_t)m * 32768;
    u8* kd = ldsK[m % 3];
#pragma unroll
    for (int jj = 0; jj < 4; ++jj) {
      int c = jj * 512 + ct;
      int kr = c >> 4, g = (c & 15) ^ (kr & 7);
      async16(kg + kr * 256 + g * 16, kd + c * 16);
    }
  };
  auto CONSV = [&](int m) {  // consumers: V tile m -> vA (128B/lane)
    const u8* vt = Vb + (size_t)m * 32768 + (size_t)vd0 * 128 + kh * 64;
    vA[0] = *(const i32x4*)(vt);
    vA[1] = *(const i32x4*)(vt + 16);
    vA[2] = *(const i32x4*)(vt + 32);
    vA[3] = *(const i32x4*)(vt + 48);
    vA[4] = *(const i32x4*)(vt + 4096);
    vA[5] = *(const i32x4*)(vt + 4112);
    vA[6] = *(const i32x4*)(vt + 4128);
    vA[7] = *(const i32x4*)(vt + 4144);
  };
  auto PROD = [&](int i) {  // producers: QK tile i -> P(i&1)
    const u8* kb = &ldsK[i % 3][kn * 256 + kh * 128];
    f32x16 s = {};
    __builtin_amdgcn_s_setprio(1);
#pragma unroll
    for (int b2 = 0; b2 < 4; ++b2) {
      i32x4 clo = *(const i32x4*)(kb + (((2 * b2) ^ kx) << 4));
      i32x4 chi = *(const i32x4*)(kb + (((2 * b2 + 1) ^ kx) << 4));
      s = mfma_mx(cat8(clo, chi), qf[b2], s);
    }
    __builtin_amdgcn_s_setprio(0);
    // P row = q (m31), 128B kv (permc128 order), chunk-XOR ^px.
    // kv = ks*32 + 8*g2 + 4*kh + {0..3}: chunk = (ks&1)*4 + (ks>>1)*2 + (g2>>1),
    // intra = (g2&1)*8 + 4*kh.
    u8* pst = &ldsP[i & 1][qg * 4096 + m31 * 128 + 4 * kh];
    const int cb = (ks & 1) * 4 + (ks >> 1) * 2;
#pragma unroll
    for (int g2 = 0; g2 < 4; ++g2) {
      float p0 = __builtin_amdgcn_exp2f(s[4 * g2] * CL2);
      float p1 = __builtin_amdgcn_exp2f(s[4 * g2 + 1] * CL2);
      float p2 = __builtin_amdgcn_exp2f(s[4 * g2 + 2] * CL2);
      float p3 = __builtin_amdgcn_exp2f(s[4 * g2 + 3] * CL2);
      l_w += (p0 + p1) + (p2 + p3);
      int pk = __builtin_amdgcn_cvt_pk_fp8_f32(p0, p1, 0, false);
      pk = __builtin_amdgcn_cvt_pk_fp8_f32(p2, p3, pk, true);
      *(u32*)(pst + (((cb + (g2 >> 1)) ^ px) << 4) + ((g2 & 1) << 3)) = (u32)pk;
    }
  };
  auto PV = [&](int i) {  // consumers: O += P(i) * V(i) (V in vA)
    const u8* pr = &ldsP[i & 1][cqg * 4096 + m31 * 128];
    __builtin_amdgcn_s_setprio(1);
#pragma unroll
    for (int b2 = 0; b2 < 2; ++b2) {
      const int ca = 4 * kh + 2 * b2;
      i32x4 plo = *(const i32x4*)(pr + ((ca ^ px) << 4));
      i32x4 phi = *(const i32x4*)(pr + (((ca + 1) ^ px) << 4));
      i32x8 pa = cat8(plo, phi);
      o0 = mfma_mx(pa, cat8(vA[2 * b2], vA[2 * b2 + 1]), o0);
      o1 = mfma_mx(pa, cat8(vA[4 + 2 * b2], vA[5 + 2 * b2]), o1);
    }
    __builtin_amdgcn_s_setprio(0);
  };

#define BARRIER() do { __builtin_amdgcn_s_barrier(); asm volatile("" ::: "memory"); } while (0)
#define PWAIT() asm volatile("s_waitcnt lgkmcnt(0)" ::: "memory")

  // ---- prologue: stage K(0),K(1) cooperatively (1024 threads x 4 chunks) ----
#pragma unroll
  for (int rep = 0; rep < 4; ++rep) {
    int c = rep * 1024 + t;  // 0..4095
    int tile = c >> 11, cc = c & 2047;
    int kr = cc >> 4, g = (cc & 15) ^ (kr & 7);
    async16(Kb + tile * 32768 + kr * 256 + g * 16, &ldsK[tile][cc * 16]);
  }
  asm volatile("s_waitcnt vmcnt(0) lgkmcnt(0)" ::: "memory");
  BARRIER();

  // ---- j = 0: no PV yet ----
  if (prod) { PROD(0); PWAIT(); }
  else { STAGE(2); CONSV(0); }
  BARRIER();

  // ---- main loop: j = 1..29 ----
#pragma unroll 1
  for (int j = 1; j <= 29; ++j) {
    if (prod) { PROD(j); PWAIT(); }
    else { STAGE(j + 2); PV(j - 1); CONSV(j); }
    BARRIER();
  }

  // ---- j = 30, 31: no more staging ----
  if (prod) { PROD(30); PWAIT(); }
  else { PV(29); CONSV(30); }
  BARRIER();
  if (prod) { PROD(31); PWAIT(); }
  else { PV(30); CONSV(31); }
  BARRIER();

  // ---- epilogue ----
  if (prod) {
    l_w += __shfl_xor(l_w, 32, 64);
    if (kh == 0) atomicAdd(&lb[qg * 32 + m31], l_w);
  } else {
    PV(31);
  }
  __syncthreads();

  if (!prod) {
    bf16* ob = Ob + (size_t)(qt * 64 + cqg * 32) * 256 + dpair * 64;
#pragma unroll
    for (int reg = 0; reg < 16; ++reg) {
      const int row = (reg & 3) + 8 * (reg >> 2) + 4 * kh;
      float li = lb[cqg * 32 + row];
      ob[(size_t)row * 256 + m31] = (bf16)(o0[reg] / li);
      ob[(size_t)row * 256 + 32 + m31] = (bf16)(o1[reg] / li);
    }
  }
#undef BARRIER
#undef PWAIT
}

// ---------------- gate: mean over S then dot Wg + sigmoid ----------------
__global__ __launch_bounds__(256) void gate_partial(const bf16* __restrict__ h,
                                                    float* __restrict__ part) {
  int bb = blockIdx.y;
  const bf16* hb = h + (size_t)bb * S_LEN * 256 + (size_t)blockIdx.x * 64 * 256;
  int t = threadIdx.x;
  float acc = 0.f;
#pragma unroll 4
  for (int s = 0; s < 64; ++s) acc += (float)hb[s * 256 + t];
  part[((size_t)bb * 64 + blockIdx.x) * 256 + t] = acc;
}

__global__ __launch_bounds__(256) void gate_final(const float* __restrict__ part,
                                                  const float* __restrict__ Wg,
                                                  const float* __restrict__ bg,
                                                  float* __restrict__ pg) {
  int bb = blockIdx.x, t = threadIdx.x;
  const float* p = part + (size_t)bb * 64 * 256;
  float acc = 0.f;
#pragma unroll 4
  for (int c = 0; c < 64; ++c) acc += p[c * 256 + t];
  acc *= Wg[t] * (1.0f / 4096.0f);
  __shared__ float red[256];
  red[t] = acc;
  __syncthreads();
  if (t < 64) {
    float a = red[t] + red[t + 64] + red[t + 128] + red[t + 192];
#pragma unroll
    for (int d = 1; d < 64; d <<= 1) a += __shfl_xor(a, d, 64);
    if (t == 0) pg[bb] = 1.0f / (1.0f + __expf(-(a + bg[0])));
  }
}

// ---------------- fused reparam + ELU + residual + LayerNorm ----------------
__global__ __launch_bounds__(256) void epilogue_kernel(const float* __restrict__ x,
                                                       const float* __restrict__ eps,
                                                       const float* __restrict__ mu,
                                                       const float* __restrict__ lv,
                                                       const float* __restrict__ gamma,
                                                       const float* __restrict__ beta,
                                                       float* __restrict__ out) {
  size_t base = (size_t)blockIdx.x * 1024 + (threadIdx.x >> 6) * 256;
  int l = threadIdx.x & 63;
  f32x4 xv = ((const f32x4*)(x + base))[l];
  f32x4 ev = ((const f32x4*)(eps + base))[l];
  f32x4 mv = ((const f32x4*)(mu + base))[l];
  f32x4 vv = ((const f32x4*)(lv + base))[l];
  f32x4 y;
  float s = 0.f, s2 = 0.f;
#pragma unroll
  for (int c = 0; c < 4; ++c) {
    float z = mv[c] + ev[c] * __expf(0.5f * vv[c]);
    z = z > 0.f ? z : (__expf(z) - 1.f);
    float yy = xv[c] + z;
    y[c] = yy;
    s += yy;
    s2 += yy * yy;
  }
#pragma unroll
  for (int d = 1; d < 64; d <<= 1) {
    s += __shfl_xor(s, d, 64);
    s2 += __shfl_xor(s2, d, 64);
  }
  float mean = s * (1.f / 256.f);
  float var = s2 * (1.f / 256.f) - mean * mean;
  float rstd = rsqrtf(var + 1e-5f);
  f32x4 gv = ((const f32x4*)gamma)[l];
  f32x4 bv = ((const f32x4*)beta)[l];
  f32x4 o;
#pragma unroll
  for (int c = 0; c < 4; ++c) o[c] = (y[c] - mean) * rstd * gv[c] + bv[c];
  ((f32x4*)(out + base))[l] = o;
}

// ---------------- launch ----------------
extern "C" void kernel_launch(void* const* d_in, const int* in_sizes, int n_in, void* d_out,
                              int out_size, void* d_ws, size_t ws_size, hipStream_t stream) {
  const float* x = (const float*)d_in[0];
  const float* eps = (const float*)d_in[1];
  const float* Wg = (const float*)d_in[18];
  const float* bg = (const float*)d_in[19];
  const float* gamma = (const float*)d_in[20];
  const float* beta = (const float*)d_in[21];

  char* ws = (char*)d_ws;
  bf16* x16 = (bf16*)(ws);                  // 8 MB
  bf16* h16 = (bf16*)(ws + 8388608);        // 8 MB
  u8* q8 = (u8*)(ws + 25165824);            // 4 MB
  u8* k8 = (u8*)(ws + 29360128);            // 4 MB
  u8* vt8 = (u8*)(ws + 33554432);           // 4 MB (V^T fp8 tile-major)
  bf16* w16 = (bf16*)(ws + 37748736);       // 1 MB (8 x 256x256 bf16)
  float* gpart = (float*)(ws + 38797312);   // 256 KB

  float* out = (float*)d_out;
  float* mu = out + 4194304;
  float* lv = out + 8388608;
  float* pg = out + 12582912;

  WPtrs wp;
  for (int i = 0; i < 8; ++i) wp.p[i] = (const float*)d_in[2 + i];
  cast_all_kernel<<<4608, 256, 0, stream>>>((const f32x4*)x, wp, (ushort4*)x16, (ushort4*)w16);

  GemmIO io1;
  io1.bias[0] = (const float*)d_in[10];
  io1.bias[1] = (const float*)d_in[11];
  io1.bias[2] = (const float*)d_in[12];
  io1.out[0] = q8; io1.out[1] = k8; io1.out[2] = vt8;
  gemm_qkv_kernel<<<dim3(128, 2, 3), 256, 0, stream>>>(x16, w16, io1);
  flash_kernel<<<256, 1024, 0, stream>>>(q8, k8, vt8, h16);

  GemmIO io2;
  io2.bias[0] = (const float*)d_in[13];
  io2.bias[1] = (const float*)d_in[14];
  io2.bias[2] = (const float*)d_in[15];
  io2.out[0] = q8; io2.out[1] = k8; io2.out[2] = vt8;
  gemm_qkv_kernel<<<dim3(128, 2, 3), 256, 0, stream>>>(h16, w16 + 3 * 65536, io2);
  flash_kernel<<<256, 1024, 0, stream>>>(q8, k8, vt8, h16);

  GemmIO io3;
  io3.bias[0] = (const float*)d_in[16];
  io3.bias[1] = (const float*)d_in[17];
  io3.bias[2] = nullptr;
  io3.out[0] = mu; io3.out[1] = lv; io3.out[2] = nullptr;
  gemm_f_kernel<<<dim3(128, 2, 2), 256, 0, stream>>>(h16, w16 + 6 * 65536, io3);

  gate_partial<<<dim3(64, 4), 256, 0, stream>>>(h16, gpart);
  gate_final<<<4, 256, 0, stream>>>(gpart, Wg, bg, pg);
  epilogue_kernel<<<4096, 256, 0, stream>>>(x, eps, mu, lv, gamma, beta, out);
}

// Round 9
// 491.110 us; speedup vs baseline: 1.0090x; 1.0090x over previous
//
#include <hip/hip_runtime.h>
#include <hip/hip_bf16.h>
#include <hip/hip_fp8.h>
#include <cstdint>
#include <cstddef>

// Problem: B=4, S=4096, D=256 two-layer full attention + VAE head. fp32 I/O.
// Strategy: MX-scaled fp8 MFMA flash attention (v16 = v15 with the flash
// register budget fixed: __launch_bounds__(1024) so the allocator gets 128
// VGPRs/wave instead of 64 -> no scratch spills); bf16 MFMA GEMMs.

#define S_LEN 4096
#define DMODEL 256
#define NBATCH 4

typedef __bf16 bf16;
typedef __bf16 bf16x8 __attribute__((ext_vector_type(8)));
typedef float f32x4 __attribute__((ext_vector_type(4)));
typedef float f32x16 __attribute__((ext_vector_type(16)));
typedef int i32x4 __attribute__((ext_vector_type(4)));
typedef int i32x8 __attribute__((ext_vector_type(8)));
typedef unsigned char u8;
typedef unsigned int u32;

__device__ __forceinline__ f32x4 mfma16(bf16x8 a, bf16x8 b, f32x4 c) {
  return __builtin_amdgcn_mfma_f32_16x16x32_bf16(a, b, c, 0, 0, 0);
}
// MX-scaled fp8 MFMA, K=64, unit scales (e8m0 0x7F = 2^0): plain fp8 matmul at 2x rate.
__device__ __forceinline__ f32x16 mfma_mx(i32x8 a, i32x8 b, f32x16 c) {
  return __builtin_amdgcn_mfma_scale_f32_32x32x64_f8f6f4(
      a, b, c, 0, 0, 0, 0x7F7F7F7F, 0, 0x7F7F7F7F);
}
__device__ __forceinline__ i32x8 cat8(i32x4 a, i32x4 b) {
  return __builtin_shufflevector(a, b, 0, 1, 2, 3, 4, 5, 6, 7);
}

// Async global->LDS, 16B per lane. LDS dest: wave-uniform base + lane*16.
__device__ __forceinline__ void async16(const void* g, void* lds) {
  __builtin_amdgcn_global_load_lds(
      (const __attribute__((address_space(1))) unsigned int*)g,
      (__attribute__((address_space(3))) unsigned int*)lds, 16, 0, 0);
}

__device__ __forceinline__ unsigned short f2bfbits(float f) {
  return __builtin_bit_cast(unsigned short, (bf16)f);
}
__device__ __forceinline__ u8 f2fp8(float f) {
  __hip_fp8_e4m3 t(f);  // OCP e4m3fn
  return *(u8*)&t;
}
// half-split column permutation over 256-wide d for K=64 scaled MFMA:
// k = b2*64 + h*32 + m -> position h*128 + b2*32 + m.
__device__ __forceinline__ int permc(int v) {
  return (((v >> 5) & 1) << 7) + (((v >> 6) & 3) << 5) + (v & 31);
}
// same over a 128-wide dim: k = b2*64 + h*32 + m -> h*64 + b2*32 + m.
__device__ __forceinline__ int permc128(int v) {
  return (((v >> 5) & 1) << 6) + (((v >> 6) & 1) << 5) + (v & 31);
}

// ---------------- cast kernel (x + 8 weight mats in one launch) ----------------
struct WPtrs { const float* p[8]; };

__global__ void cast_all_kernel(const f32x4* __restrict__ x, WPtrs wp,
                                ushort4* __restrict__ x16, ushort4* __restrict__ w16) {
  int bx = blockIdx.x, t = threadIdx.x;
  const f32x4* src;
  ushort4* dst;
  if (bx < 4096) {
    src = x + (size_t)bx * 256 + t;
    dst = x16 + (size_t)bx * 256 + t;
  } else {
    int r = bx - 4096;
    int m = r >> 6;
    int i = (r & 63) * 256 + t;
    src = (const f32x4*)wp.p[m] + i;
    dst = w16 + (size_t)m * 16384 + i;
  }
  f32x4 v = *src;
  ushort4 o;
  o.x = f2bfbits(v[0]); o.y = f2bfbits(v[1]); o.z = f2bfbits(v[2]); o.w = f2bfbits(v[3]);
  *dst = o;
}

// ---------------- GEMM: out[m][n] = sum_k A[m][k]*W[n][k] + bias[n] ----------------
// z=0: Q fp8 (plain [M][256]); z=1: K fp8 (permc cols, [M][256]);
// z=2: V fp8 transposed tile-major [B][S/128][256 d][128 kv permc128].
struct GemmIO {
  const float* bias[3];
  void* out[3];
};

__global__ __launch_bounds__(256, 3) void gemm_qkv_kernel(const bf16* __restrict__ A,
                                                          const bf16* __restrict__ Wb,
                                                          GemmIO io) {
  __shared__ bf16 ldsA[128 * 64];
  __shared__ bf16 ldsB[128 * 64];
  const int t = threadIdx.x;
  const int m0 = blockIdx.x * 128;
  const int n0 = blockIdx.y * 128;
  const bf16* W = Wb + (size_t)blockIdx.z * 65536;
  const int w = t >> 6, l = t & 63, lm = l & 15, q = l >> 4;
  const int wr = (w >> 1) * 64, wc = (w & 1) * 64;

  f32x4 acc[4][4] = {};
#pragma unroll 1
  for (int it = 0; it < 4; ++it) {
    const int k0 = it * 64;
#pragma unroll
    for (int c = 0; c < 4; ++c) {
      int i = c * 256 + t;
      int r = i >> 3, c8 = (i & 7) ^ (r & 7);
      async16(A + (size_t)(m0 + r) * 256 + k0 + c8 * 8, &ldsA[i * 8]);
    }
#pragma unroll
    for (int c = 0; c < 4; ++c) {
      int i = c * 256 + t;
      int r = i >> 3, c8 = (i & 7) ^ (r & 7);
      async16(W + (size_t)(n0 + r) * 256 + k0 + c8 * 8, &ldsB[i * 8]);
    }
    __syncthreads();
#pragma unroll
    for (int ks = 0; ks < 2; ++ks) {
      bf16x8 af[4], bfr[4];
#pragma unroll
      for (int i = 0; i < 4; ++i) {
        int ra = wr + i * 16 + lm;
        af[i] = *(const bf16x8*)&ldsA[ra * 64 + ((((ks << 2) + q) ^ (ra & 7)) << 3)];
        int rb = wc + i * 16 + lm;
        bfr[i] = *(const bf16x8*)&ldsB[rb * 64 + ((((ks << 2) + q) ^ (rb & 7)) << 3)];
      }
#pragma unroll
      for (int i = 0; i < 4; ++i)
#pragma unroll
        for (int jj = 0; jj < 4; ++jj) acc[i][jj] = mfma16(af[i], bfr[jj], acc[i][jj]);
    }
    __syncthreads();
  }
  const float* bias = io.bias[blockIdx.z];
  if (blockIdx.z == 2) {
    // V: write fp8 V^T tile-major directly (fused transpose), kv permc128 per 128.
    u8* out = (u8*)io.out[2];
#pragma unroll
    for (int jj = 0; jj < 4; ++jj) {
      int col = n0 + wc + jj * 16 + lm;
      float bv = bias[col];
#pragma unroll
      for (int i = 0; i < 4; ++i) {
        int row = m0 + wr + i * 16 + q * 4;
#pragma unroll
        for (int r = 0; r < 4; ++r) {
          int rg = row + r;
          int bb = rg >> 12, s = rg & 4095;
          out[(((size_t)(bb * 32 + (s >> 7)) * 256 + col) << 7) + permc128(s & 127)] =
              f2fp8(acc[i][jj][r] + bv);
        }
      }
    }
  } else {
    u8* out = (u8*)io.out[blockIdx.z];
#pragma unroll
    for (int jj = 0; jj < 4; ++jj) {
      int col = n0 + wc + jj * 16 + lm;
      int scol = (blockIdx.z == 1) ? permc(col) : col;  // K gets half-split cols
      float bv = bias[col];
#pragma unroll
      for (int i = 0; i < 4; ++i) {
        int row = m0 + wr + i * 16 + q * 4;
#pragma unroll
        for (int r = 0; r < 4; ++r)
          out[(size_t)(row + r) * 256 + scol] = f2fp8(acc[i][jj][r] + bv);
      }
    }
  }
}

// mu/lv GEMM (fp32 out) — same structure.
__global__ __launch_bounds__(256, 3) void gemm_f_kernel(const bf16* __restrict__ A,
                                                        const bf16* __restrict__ Wb, GemmIO io) {
  __shared__ bf16 ldsA[128 * 64];
  __shared__ bf16 ldsB[128 * 64];
  const int t = threadIdx.x;
  const int m0 = blockIdx.x * 128;
  const int n0 = blockIdx.y * 128;
  const bf16* W = Wb + (size_t)blockIdx.z * 65536;
  const int w = t >> 6, l = t & 63, lm = l & 15, q = l >> 4;
  const int wr = (w >> 1) * 64, wc = (w & 1) * 64;

  f32x4 acc[4][4] = {};
#pragma unroll 1
  for (int it = 0; it < 4; ++it) {
    const int k0 = it * 64;
#pragma unroll
    for (int c = 0; c < 4; ++c) {
      int i = c * 256 + t;
      int r = i >> 3, c8 = (i & 7) ^ (r & 7);
      async16(A + (size_t)(m0 + r) * 256 + k0 + c8 * 8, &ldsA[i * 8]);
    }
#pragma unroll
    for (int c = 0; c < 4; ++c) {
      int i = c * 256 + t;
      int r = i >> 3, c8 = (i & 7) ^ (r & 7);
      async16(W + (size_t)(n0 + r) * 256 + k0 + c8 * 8, &ldsB[i * 8]);
    }
    __syncthreads();
#pragma unroll
    for (int ks = 0; ks < 2; ++ks) {
      bf16x8 af[4], bfr[4];
#pragma unroll
      for (int i = 0; i < 4; ++i) {
        int ra = wr + i * 16 + lm;
        af[i] = *(const bf16x8*)&ldsA[ra * 64 + ((((ks << 2) + q) ^ (ra & 7)) << 3)];
        int rb = wc + i * 16 + lm;
        bfr[i] = *(const bf16x8*)&ldsB[rb * 64 + ((((ks << 2) + q) ^ (rb & 7)) << 3)];
      }
#pragma unroll
      for (int i = 0; i < 4; ++i)
#pragma unroll
        for (int jj = 0; jj < 4; ++jj) acc[i][jj] = mfma16(af[i], bfr[jj], acc[i][jj]);
    }
    __syncthreads();
  }
  const float* bias = io.bias[blockIdx.z];
  float* out = (float*)io.out[blockIdx.z];
#pragma unroll
  for (int jj = 0; jj < 4; ++jj) {
    int col = n0 + wc + jj * 16 + lm;
    float bv = bias[col];
#pragma unroll
    for (int i = 0; i < 4; ++i) {
      int row = m0 + wr + i * 16 + q * 4;
#pragma unroll
      for (int r = 0; r < 4; ++r)
        out[(size_t)(row + r) * 256 + col] = acc[i][jj][r] + bv;
    }
  }
}

// ---------------- flash attention v16 (= v15, 128-VGPR budget) ----------------
// 256 blocks (1/CU), 1024 threads = 16 waves. BM=64 Q rows, KV tile 128, 32 iters.
// Waves 0-7 = producers (qg=w&1, ks=w>>1): QK S^T strip mfma_mx(A=K_lds[j%3],
// B=Q_regs) k=256 chained into one f32x16; softmax in 4-reg groups; P ->
// ldsP[j&1] (permc128 kv, chunk^q swizzle); lgkmcnt(0) before barrier.
// Waves 8-15 = consumers (cqg=cw&1, dpair=cw>>1): STAGE K(j+2) -> ring slot
// (j+2)%3 (4 async16/lane); PV(j-1) = mfma_mx(A=P_lds, B=vA) k=128 into o0/o1;
// then CONSV(j) global->vA (single reg buffer; WAR after MFMA issue is safe).
// No manual vmcnt: the compiler's RAW wait before PV's MFMAs retires (in-order)
// iter j-1's CONSV and with it all older K staging -> K(j+1) ready pre-barrier.
// One s_barrier per iteration.
// NOTE: __launch_bounds__(1024) (no 2nd arg). With (1024,4) hipcc budgets 64
// VGPRs (r7: VGPR_Count=64, WRITE_SIZE=130MB of scratch spill, flash 165us).
// A 1024-thread block needs VGPR<=128 to be launchable, so (1024) gives the
// allocator the full 128 and the ~110-reg live set (qf+vA+addr, o in AGPR) fits.
__global__ __launch_bounds__(1024) void flash_kernel(const u8* __restrict__ Q,
                                                     const u8* __restrict__ K,
                                                     const u8* __restrict__ Vt,
                                                     bf16* __restrict__ O) {
  __shared__ __align__(16) u8 ldsK[3][32768];         // 96KB: 3-slot K ring
  __shared__ __align__(16) u8 ldsP[2][2 * 32 * 128];  // 16KB: P double buffer
  __shared__ float lb[64];

  const int id = blockIdx.x;
  const int xcd = id & 7;
  const int b = xcd >> 1;
  const int qt = (id >> 3) + ((xcd & 1) << 5);  // 0..63

  const u8* Qb = Q + (size_t)b * S_LEN * 256;
  const u8* Kb = K + (size_t)b * S_LEN * 256;
  const u8* Vb = Vt + (size_t)b * 1048576;  // [32 tiles][256 d][128 kv]
  bf16* Ob = O + (size_t)b * S_LEN * 256;

  const int t = threadIdx.x, w = t >> 6, lane = t & 63;
  const int m31 = lane & 31, kh = lane >> 5;
  const bool prod = (w < 8);
  const float CL2 = 0.09016844005556021f;  // log2(e)/sqrt(D)

  if (t < 64) lb[t] = 0.f;

  // ---- producer setup (waves 0-7) ----
  const int qg = w & 1, ks = (w >> 1) & 3;
  const int kn = ks * 32 + m31;  // kv row in K tile
  const int kx = kn & 7;
  const int px = m31 & 7;
  i32x8 qf[4];
  if (prod) {
    const u8* qrow = Qb + (size_t)(qt * 64 + qg * 32 + m31) * 256 + kh * 32;
#pragma unroll
    for (int b2 = 0; b2 < 4; ++b2) qf[b2] = *(const i32x8*)(qrow + b2 * 64);
  }
  float l_w = 0.f;

  // ---- consumer setup (waves 8-15) ----
  const int cw = w - 8;
  const int cqg = cw & 1, dpair = cw >> 1;  // dpair 0..3
  const int vd0 = dpair * 64 + m31;         // V^T d-row
  const int ct = (t - 512) & 511;           // consumer linear id 0..511
  f32x16 o0 = {}, o1 = {};
  i32x4 vA[8];

  auto STAGE = [&](int m) {  // consumers: stage K tile m into ring slot m%3
    const u8* kg = Kb + (size_t)m * 32768;
    u8* kd = ldsK[m % 3];
#pragma unroll
    for (int jj = 0; jj < 4; ++jj) {
      int c = jj * 512 + ct;
      int kr = c >> 4, g = (c & 15) ^ (kr & 7);
      async16(kg + kr * 256 + g * 16, kd + c * 16);
    }
  };
  auto CONSV = [&](int m) {  // consumers: V tile m -> vA (128B/lane)
    const u8* vt = Vb + (size_t)m * 32768 + (size_t)vd0 * 128 + kh * 64;
    vA[0] = *(const i32x4*)(vt);
    vA[1] = *(const i32x4*)(vt + 16);
    vA[2] = *(const i32x4*)(vt + 32);
    vA[3] = *(const i32x4*)(vt + 48);
    vA[4] = *(const i32x4*)(vt + 4096);
    vA[5] = *(const i32x4*)(vt + 4112);
    vA[6] = *(const i32x4*)(vt + 4128);
    vA[7] = *(const i32x4*)(vt + 4144);
  };
  auto PROD = [&](int i) {  // producers: QK tile i -> P(i&1)
    const u8* kb = &ldsK[i % 3][kn * 256 + kh * 128];
    f32x16 s = {};
    __builtin_amdgcn_s_setprio(1);
#pragma unroll
    for (int b2 = 0; b2 < 4; ++b2) {
      i32x4 clo = *(const i32x4*)(kb + (((2 * b2) ^ kx) << 4));
      i32x4 chi = *(const i32x4*)(kb + (((2 * b2 + 1) ^ kx) << 4));
      s = mfma_mx(cat8(clo, chi), qf[b2], s);
    }
    __builtin_amdgcn_s_setprio(0);
    // P row = q (m31), 128B kv (permc128 order), chunk-XOR ^px.
    // kv = ks*32 + 8*g2 + 4*kh + {0..3}: chunk = (ks&1)*4 + (ks>>1)*2 + (g2>>1),
    // intra = (g2&1)*8 + 4*kh.
    u8* pst = &ldsP[i & 1][qg * 4096 + m31 * 128 + 4 * kh];
    const int cb = (ks & 1) * 4 + (ks >> 1) * 2;
#pragma unroll
    for (int g2 = 0; g2 < 4; ++g2) {
      float p0 = __builtin_amdgcn_exp2f(s[4 * g2] * CL2);
      float p1 = __builtin_amdgcn_exp2f(s[4 * g2 + 1] * CL2);
      float p2 = __builtin_amdgcn_exp2f(s[4 * g2 + 2] * CL2);
      float p3 = __builtin_amdgcn_exp2f(s[4 * g2 + 3] * CL2);
      l_w += (p0 + p1) + (p2 + p3);
      int pk = __builtin_amdgcn_cvt_pk_fp8_f32(p0, p1, 0, false);
      pk = __builtin_amdgcn_cvt_pk_fp8_f32(p2, p3, pk, true);
      *(u32*)(pst + (((cb + (g2 >> 1)) ^ px) << 4) + ((g2 & 1) << 3)) = (u32)pk;
    }
  };
  auto PV = [&](int i) {  // consumers: O += P(i) * V(i) (V in vA)
    const u8* pr = &ldsP[i & 1][cqg * 4096 + m31 * 128];
    __builtin_amdgcn_s_setprio(1);
#pragma unroll
    for (int b2 = 0; b2 < 2; ++b2) {
      const int ca = 4 * kh + 2 * b2;
      i32x4 plo = *(const i32x4*)(pr + ((ca ^ px) << 4));
      i32x4 phi = *(const i32x4*)(pr + (((ca + 1) ^ px) << 4));
      i32x8 pa = cat8(plo, phi);
      o0 = mfma_mx(pa, cat8(vA[2 * b2], vA[2 * b2 + 1]), o0);
      o1 = mfma_mx(pa, cat8(vA[4 + 2 * b2], vA[5 + 2 * b2]), o1);
    }
    __builtin_amdgcn_s_setprio(0);
  };

#define BARRIER() do { __builtin_amdgcn_s_barrier(); asm volatile("" ::: "memory"); } while (0)
#define PWAIT() asm volatile("s_waitcnt lgkmcnt(0)" ::: "memory")

  // ---- prologue: stage K(0),K(1) cooperatively (1024 threads x 4 chunks) ----
#pragma unroll
  for (int rep = 0; rep < 4; ++rep) {
    int c = rep * 1024 + t;  // 0..4095
    int tile = c >> 11, cc = c & 2047;
    int kr = cc >> 4, g = (cc & 15) ^ (kr & 7);
    async16(Kb + tile * 32768 + kr * 256 + g * 16, &ldsK[tile][cc * 16]);
  }
  asm volatile("s_waitcnt vmcnt(0) lgkmcnt(0)" ::: "memory");
  BARRIER();

  // ---- j = 0: no PV yet ----
  if (prod) { PROD(0); PWAIT(); }
  else { STAGE(2); CONSV(0); }
  BARRIER();

  // ---- main loop: j = 1..29 ----
#pragma unroll 1
  for (int j = 1; j <= 29; ++j) {
    if (prod) { PROD(j); PWAIT(); }
    else { STAGE(j + 2); PV(j - 1); CONSV(j); }
    BARRIER();
  }

  // ---- j = 30, 31: no more staging ----
  if (prod) { PROD(30); PWAIT(); }
  else { PV(29); CONSV(30); }
  BARRIER();
  if (prod) { PROD(31); PWAIT(); }
  else { PV(30); CONSV(31); }
  BARRIER();

  // ---- epilogue ----
  if (prod) {
    l_w += __shfl_xor(l_w, 32, 64);
    if (kh == 0) atomicAdd(&lb[qg * 32 + m31], l_w);
  } else {
    PV(31);
  }
  __syncthreads();

  if (!prod) {
    bf16* ob = Ob + (size_t)(qt * 64 + cqg * 32) * 256 + dpair * 64;
#pragma unroll
    for (int reg = 0; reg < 16; ++reg) {
      const int row = (reg & 3) + 8 * (reg >> 2) + 4 * kh;
      float li = lb[cqg * 32 + row];
      ob[(size_t)row * 256 + m31] = (bf16)(o0[reg] / li);
      ob[(size_t)row * 256 + 32 + m31] = (bf16)(o1[reg] / li);
    }
  }
#undef BARRIER
#undef PWAIT
}

// ---------------- gate: mean over S then dot Wg + sigmoid ----------------
__global__ __launch_bounds__(256) void gate_partial(const bf16* __restrict__ h,
                                                    float* __restrict__ part) {
  int bb = blockIdx.y;
  const bf16* hb = h + (size_t)bb * S_LEN * 256 + (size_t)blockIdx.x * 64 * 256;
  int t = threadIdx.x;
  float acc = 0.f;
#pragma unroll 4
  for (int s = 0; s < 64; ++s) acc += (float)hb[s * 256 + t];
  part[((size_t)bb * 64 + blockIdx.x) * 256 + t] = acc;
}

__global__ __launch_bounds__(256) void gate_final(const float* __restrict__ part,
                                                  const float* __restrict__ Wg,
                                                  const float* __restrict__ bg,
                                                  float* __restrict__ pg) {
  int bb = blockIdx.x, t = threadIdx.x;
  const float* p = part + (size_t)bb * 64 * 256;
  float acc = 0.f;
#pragma unroll 4
  for (int c = 0; c < 64; ++c) acc += p[c * 256 + t];
  acc *= Wg[t] * (1.0f / 4096.0f);
  __shared__ float red[256];
  red[t] = acc;
  __syncthreads();
  if (t < 64) {
    float a = red[t] + red[t + 64] + red[t + 128] + red[t + 192];
#pragma unroll
    for (int d = 1; d < 64; d <<= 1) a += __shfl_xor(a, d, 64);
    if (t == 0) pg[bb] = 1.0f / (1.0f + __expf(-(a + bg[0])));
  }
}

// ---------------- fused reparam + ELU + residual + LayerNorm ----------------
__global__ __launch_bounds__(256) void epilogue_kernel(const float* __restrict__ x,
                                                       const float* __restrict__ eps,
                                                       const float* __restrict__ mu,
                                                       const float* __restrict__ lv,
                                                       const float* __restrict__ gamma,
                                                       const float* __restrict__ beta,
                                                       float* __restrict__ out) {
  size_t base = (size_t)blockIdx.x * 1024 + (threadIdx.x >> 6) * 256;
  int l = threadIdx.x & 63;
  f32x4 xv = ((const f32x4*)(x + base))[l];
  f32x4 ev = ((const f32x4*)(eps + base))[l];
  f32x4 mv = ((const f32x4*)(mu + base))[l];
  f32x4 vv = ((const f32x4*)(lv + base))[l];
  f32x4 y;
  float s = 0.f, s2 = 0.f;
#pragma unroll
  for (int c = 0; c < 4; ++c) {
    float z = mv[c] + ev[c] * __expf(0.5f * vv[c]);
    z = z > 0.f ? z : (__expf(z) - 1.f);
    float yy = xv[c] + z;
    y[c] = yy;
    s += yy;
    s2 += yy * yy;
  }
#pragma unroll
  for (int d = 1; d < 64; d <<= 1) {
    s += __shfl_xor(s, d, 64);
    s2 += __shfl_xor(s2, d, 64);
  }
  float mean = s * (1.f / 256.f);
  float var = s2 * (1.f / 256.f) - mean * mean;
  float rstd = rsqrtf(var + 1e-5f);
  f32x4 gv = ((const f32x4*)gamma)[l];
  f32x4 bv = ((const f32x4*)beta)[l];
  f32x4 o;
#pragma unroll
  for (int c = 0; c < 4; ++c) o[c] = (y[c] - mean) * rstd * gv[c] + bv[c];
  ((f32x4*)(out + base))[l] = o;
}

// ---------------- launch ----------------
extern "C" void kernel_launch(void* const* d_in, const int* in_sizes, int n_in, void* d_out,
                              int out_size, void* d_ws, size_t ws_size, hipStream_t stream) {
  const float* x = (const float*)d_in[0];
  const float* eps = (const float*)d_in[1];
  const float* Wg = (const float*)d_in[18];
  const float* bg = (const float*)d_in[19];
  const float* gamma = (const float*)d_in[20];
  const float* beta = (const float*)d_in[21];

  char* ws = (char*)d_ws;
  bf16* x16 = (bf16*)(ws);                  // 8 MB
  bf16* h16 = (bf16*)(ws + 8388608);        // 8 MB
  u8* q8 = (u8*)(ws + 25165824);            // 4 MB
  u8* k8 = (u8*)(ws + 29360128);            // 4 MB
  u8* vt8 = (u8*)(ws + 33554432);           // 4 MB (V^T fp8 tile-major)
  bf16* w16 = (bf16*)(ws + 37748736);       // 1 MB (8 x 256x256 bf16)
  float* gpart = (float*)(ws + 38797312);   // 256 KB

  float* out = (float*)d_out;
  float* mu = out + 4194304;
  float* lv = out + 8388608;
  float* pg = out + 12582912;

  WPtrs wp;
  for (int i = 0; i < 8; ++i) wp.p[i] = (const float*)d_in[2 + i];
  cast_all_kernel<<<4608, 256, 0, stream>>>((const f32x4*)x, wp, (ushort4*)x16, (ushort4*)w16);

  GemmIO io1;
  io1.bias[0] = (const float*)d_in[10];
  io1.bias[1] = (const float*)d_in[11];
  io1.bias[2] = (const float*)d_in[12];
  io1.out[0] = q8; io1.out[1] = k8; io1.out[2] = vt8;
  gemm_qkv_kernel<<<dim3(128, 2, 3), 256, 0, stream>>>(x16, w16, io1);
  flash_kernel<<<256, 1024, 0, stream>>>(q8, k8, vt8, h16);

  GemmIO io2;
  io2.bias[0] = (const float*)d_in[13];
  io2.bias[1] = (const float*)d_in[14];
  io2.bias[2] = (const float*)d_in[15];
  io2.out[0] = q8; io2.out[1] = k8; io2.out[2] = vt8;
  gemm_qkv_kernel<<<dim3(128, 2, 3), 256, 0, stream>>>(h16, w16 + 3 * 65536, io2);
  flash_kernel<<<256, 1024, 0, stream>>>(q8, k8, vt8, h16);

  GemmIO io3;
  io3.bias[0] = (const float*)d_in[16];
  io3.bias[1] = (const float*)d_in[17];
  io3.bias[2] = nullptr;
  io3.out[0] = mu; io3.out[1] = lv; io3.out[2] = nullptr;
  gemm_f_kernel<<<dim3(128, 2, 2), 256, 0, stream>>>(h16, w16 + 6 * 65536, io3);

  gate_partial<<<dim3(64, 4), 256, 0, stream>>>(h16, gpart);
  gate_final<<<4, 256, 0, stream>>>(gpart, Wg, bg, pg);
  epilogue_kernel<<<4096, 256, 0, stream>>>(x, eps, mu, lv, gamma, beta, out);
}

// Round 11
// 332.438 us; speedup vs baseline: 1.4906x; 1.4773x over previous
//
#include <hip/hip_runtime.h>
#include <hip/hip_bf16.h>
#include <hip/hip_fp8.h>
#include <cstdint>
#include <cstddef>

// Problem: B=4, S=4096, D=256 two-layer full attention + VAE head. fp32 I/O.
// Strategy: MX-scaled fp8 MFMA flash attention (v18: v15 pipeline with
// ROLE-SPLIT loops — producers and consumers each run their own barrier loop,
// making qf/vA liveness disjoint so the live set fits the register budget
// without spills — plus amdgpu_waves_per_eu(4,4)); bf16 MFMA GEMMs.

#define S_LEN 4096
#define DMODEL 256
#define NBATCH 4

typedef __bf16 bf16;
typedef __bf16 bf16x8 __attribute__((ext_vector_type(8)));
typedef float f32x4 __attribute__((ext_vector_type(4)));
typedef float f32x16 __attribute__((ext_vector_type(16)));
typedef int i32x4 __attribute__((ext_vector_type(4)));
typedef int i32x8 __attribute__((ext_vector_type(8)));
typedef unsigned char u8;
typedef unsigned int u32;

__device__ __forceinline__ f32x4 mfma16(bf16x8 a, bf16x8 b, f32x4 c) {
  return __builtin_amdgcn_mfma_f32_16x16x32_bf16(a, b, c, 0, 0, 0);
}
// MX-scaled fp8 MFMA, K=64, unit scales (e8m0 0x7F = 2^0): plain fp8 matmul at 2x rate.
__device__ __forceinline__ f32x16 mfma_mx(i32x8 a, i32x8 b, f32x16 c) {
  return __builtin_amdgcn_mfma_scale_f32_32x32x64_f8f6f4(
      a, b, c, 0, 0, 0, 0x7F7F7F7F, 0, 0x7F7F7F7F);
}
__device__ __forceinline__ i32x8 cat8(i32x4 a, i32x4 b) {
  return __builtin_shufflevector(a, b, 0, 1, 2, 3, 4, 5, 6, 7);
}

// Async global->LDS, 16B per lane. LDS dest: wave-uniform base + lane*16.
__device__ __forceinline__ void async16(const void* g, void* lds) {
  __builtin_amdgcn_global_load_lds(
      (const __attribute__((address_space(1))) unsigned int*)g,
      (__attribute__((address_space(3))) unsigned int*)lds, 16, 0, 0);
}

__device__ __forceinline__ unsigned short f2bfbits(float f) {
  return __builtin_bit_cast(unsigned short, (bf16)f);
}
__device__ __forceinline__ u8 f2fp8(float f) {
  __hip_fp8_e4m3 t(f);  // OCP e4m3fn
  return *(u8*)&t;
}
// half-split column permutation over 256-wide d for K=64 scaled MFMA:
// k = b2*64 + h*32 + m -> position h*128 + b2*32 + m.
__device__ __forceinline__ int permc(int v) {
  return (((v >> 5) & 1) << 7) + (((v >> 6) & 3) << 5) + (v & 31);
}
// same over a 128-wide dim: k = b2*64 + h*32 + m -> h*64 + b2*32 + m.
__device__ __forceinline__ int permc128(int v) {
  return (((v >> 5) & 1) << 6) + (((v >> 6) & 1) << 5) + (v & 31);
}

// ---------------- cast kernel (x + 8 weight mats in one launch) ----------------
struct WPtrs { const float* p[8]; };

__global__ void cast_all_kernel(const f32x4* __restrict__ x, WPtrs wp,
                                ushort4* __restrict__ x16, ushort4* __restrict__ w16) {
  int bx = blockIdx.x, t = threadIdx.x;
  const f32x4* src;
  ushort4* dst;
  if (bx < 4096) {
    src = x + (size_t)bx * 256 + t;
    dst = x16 + (size_t)bx * 256 + t;
  } else {
    int r = bx - 4096;
    int m = r >> 6;
    int i = (r & 63) * 256 + t;
    src = (const f32x4*)wp.p[m] + i;
    dst = w16 + (size_t)m * 16384 + i;
  }
  f32x4 v = *src;
  ushort4 o;
  o.x = f2bfbits(v[0]); o.y = f2bfbits(v[1]); o.z = f2bfbits(v[2]); o.w = f2bfbits(v[3]);
  *dst = o;
}

// ---------------- GEMM: out[m][n] = sum_k A[m][k]*W[n][k] + bias[n] ----------------
// z=0: Q fp8 (plain [M][256]); z=1: K fp8 (permc cols, [M][256]);
// z=2: V fp8 transposed tile-major [B][S/128][256 d][128 kv permc128].
struct GemmIO {
  const float* bias[3];
  void* out[3];
};

__global__ __launch_bounds__(256, 3) void gemm_qkv_kernel(const bf16* __restrict__ A,
                                                          const bf16* __restrict__ Wb,
                                                          GemmIO io) {
  __shared__ bf16 ldsA[128 * 64];
  __shared__ bf16 ldsB[128 * 64];
  const int t = threadIdx.x;
  const int m0 = blockIdx.x * 128;
  const int n0 = blockIdx.y * 128;
  const bf16* W = Wb + (size_t)blockIdx.z * 65536;
  const int w = t >> 6, l = t & 63, lm = l & 15, q = l >> 4;
  const int wr = (w >> 1) * 64, wc = (w & 1) * 64;

  f32x4 acc[4][4] = {};
#pragma unroll 1
  for (int it = 0; it < 4; ++it) {
    const int k0 = it * 64;
#pragma unroll
    for (int c = 0; c < 4; ++c) {
      int i = c * 256 + t;
      int r = i >> 3, c8 = (i & 7) ^ (r & 7);
      async16(A + (size_t)(m0 + r) * 256 + k0 + c8 * 8, &ldsA[i * 8]);
    }
#pragma unroll
    for (int c = 0; c < 4; ++c) {
      int i = c * 256 + t;
      int r = i >> 3, c8 = (i & 7) ^ (r & 7);
      async16(W + (size_t)(n0 + r) * 256 + k0 + c8 * 8, &ldsB[i * 8]);
    }
    __syncthreads();
#pragma unroll
    for (int ks = 0; ks < 2; ++ks) {
      bf16x8 af[4], bfr[4];
#pragma unroll
      for (int i = 0; i < 4; ++i) {
        int ra = wr + i * 16 + lm;
        af[i] = *(const bf16x8*)&ldsA[ra * 64 + ((((ks << 2) + q) ^ (ra & 7)) << 3)];
        int rb = wc + i * 16 + lm;
        bfr[i] = *(const bf16x8*)&ldsB[rb * 64 + ((((ks << 2) + q) ^ (rb & 7)) << 3)];
      }
#pragma unroll
      for (int i = 0; i < 4; ++i)
#pragma unroll
        for (int jj = 0; jj < 4; ++jj) acc[i][jj] = mfma16(af[i], bfr[jj], acc[i][jj]);
    }
    __syncthreads();
  }
  const float* bias = io.bias[blockIdx.z];
  if (blockIdx.z == 2) {
    // V: write fp8 V^T tile-major directly (fused transpose), kv permc128 per 128.
    u8* out = (u8*)io.out[2];
#pragma unroll
    for (int jj = 0; jj < 4; ++jj) {
      int col = n0 + wc + jj * 16 + lm;
      float bv = bias[col];
#pragma unroll
      for (int i = 0; i < 4; ++i) {
        int row = m0 + wr + i * 16 + q * 4;
#pragma unroll
        for (int r = 0; r < 4; ++r) {
          int rg = row + r;
          int bb = rg >> 12, s = rg & 4095;
          out[(((size_t)(bb * 32 + (s >> 7)) * 256 + col) << 7) + permc128(s & 127)] =
              f2fp8(acc[i][jj][r] + bv);
        }
      }
    }
  } else {
    u8* out = (u8*)io.out[blockIdx.z];
#pragma unroll
    for (int jj = 0; jj < 4; ++jj) {
      int col = n0 + wc + jj * 16 + lm;
      int scol = (blockIdx.z == 1) ? permc(col) : col;  // K gets half-split cols
      float bv = bias[col];
#pragma unroll
      for (int i = 0; i < 4; ++i) {
        int row = m0 + wr + i * 16 + q * 4;
#pragma unroll
        for (int r = 0; r < 4; ++r)
          out[(size_t)(row + r) * 256 + scol] = f2fp8(acc[i][jj][r] + bv);
      }
    }
  }
}

// mu/lv GEMM (fp32 out) — same structure.
__global__ __launch_bounds__(256, 3) void gemm_f_kernel(const bf16* __restrict__ A,
                                                        const bf16* __restrict__ Wb, GemmIO io) {
  __shared__ bf16 ldsA[128 * 64];
  __shared__ bf16 ldsB[128 * 64];
  const int t = threadIdx.x;
  const int m0 = blockIdx.x * 128;
  const int n0 = blockIdx.y * 128;
  const bf16* W = Wb + (size_t)blockIdx.z * 65536;
  const int w = t >> 6, l = t & 63, lm = l & 15, q = l >> 4;
  const int wr = (w >> 1) * 64, wc = (w & 1) * 64;

  f32x4 acc[4][4] = {};
#pragma unroll 1
  for (int it = 0; it < 4; ++it) {
    const int k0 = it * 64;
#pragma unroll
    for (int c = 0; c < 4; ++c) {
      int i = c * 256 + t;
      int r = i >> 3, c8 = (i & 7) ^ (r & 7);
      async16(A + (size_t)(m0 + r) * 256 + k0 + c8 * 8, &ldsA[i * 8]);
    }
#pragma unroll
    for (int c = 0; c < 4; ++c) {
      int i = c * 256 + t;
      int r = i >> 3, c8 = (i & 7) ^ (r & 7);
      async16(W + (size_t)(n0 + r) * 256 + k0 + c8 * 8, &ldsB[i * 8]);
    }
    __syncthreads();
#pragma unroll
    for (int ks = 0; ks < 2; ++ks) {
      bf16x8 af[4], bfr[4];
#pragma unroll
      for (int i = 0; i < 4; ++i) {
        int ra = wr + i * 16 + lm;
        af[i] = *(const bf16x8*)&ldsA[ra * 64 + ((((ks << 2) + q) ^ (ra & 7)) << 3)];
        int rb = wc + i * 16 + lm;
        bfr[i] = *(const bf16x8*)&ldsB[rb * 64 + ((((ks << 2) + q) ^ (rb & 7)) << 3)];
      }
#pragma unroll
      for (int i = 0; i < 4; ++i)
#pragma unroll
        for (int jj = 0; jj < 4; ++jj) acc[i][jj] = mfma16(af[i], bfr[jj], acc[i][jj]);
    }
    __syncthreads();
  }
  const float* bias = io.bias[blockIdx.z];
  float* out = (float*)io.out[blockIdx.z];
#pragma unroll
  for (int jj = 0; jj < 4; ++jj) {
    int col = n0 + wc + jj * 16 + lm;
    float bv = bias[col];
#pragma unroll
    for (int i = 0; i < 4; ++i) {
      int row = m0 + wr + i * 16 + q * 4;
#pragma unroll
      for (int r = 0; r < 4; ++r)
        out[(size_t)(row + r) * 256 + col] = acc[i][jj][r] + bv;
    }
  }
}

// ---------------- flash attention v18: role-split loops ----------------
// 256 blocks (1/CU), 1024 threads = 16 waves. BM=64 Q rows, KV tile 128, 32 iters.
// v15 pipeline, but producers and consumers each run a SEPARATE loop with
// matched barrier counts (33 each: 32 K-iterations + 1 for the l-reduction).
// This makes qf (producer, 32 regs) and vA (consumer, 32 regs) liveness
// DISJOINT: per-point live set ~max(68,45) instead of union ~110, so no
// scratch spills even at a 64-VGPR budget (r7/r9: merged loop spilled 130MB).
// amdgpu_waves_per_eu(4,4) additionally unlocks 128 VGPRs (LDS=112.5KB forces
// 1 block/CU = 4 waves/EU regardless, so the max-pin costs nothing).
// Pipeline (global barrier sequence identical to v15, invariant re-verified):
// producers at iter j: QK(j) from K ring slot j%3, softmax, P -> ldsP[j&1],
// lgkmcnt(0), barrier. Consumers at iter j: STAGE K(j+2) -> slot (j+2)%3;
// PV(j-1) (waits CONSV(j-1) -> in-order retires STAGE(j+1)); CONSV(j); barrier.
__global__ __attribute__((amdgpu_waves_per_eu(4, 4)))
__launch_bounds__(1024) void flash_kernel(const u8* __restrict__ Q,
                                          const u8* __restrict__ K,
                                          const u8* __restrict__ Vt,
                                          bf16* __restrict__ O) {
  __shared__ __align__(16) u8 ldsK[3][32768];         // 96KB: 3-slot K ring
  __shared__ __align__(16) u8 ldsP[2][2 * 32 * 128];  // 16KB: P double buffer
  __shared__ float lb[64];

  const int id = blockIdx.x;
  const int xcd = id & 7;
  const int b = xcd >> 1;
  const int qt = (id >> 3) + ((xcd & 1) << 5);  // 0..63

  const u8* Qb = Q + (size_t)b * S_LEN * 256;
  const u8* Kb = K + (size_t)b * S_LEN * 256;
  const u8* Vb = Vt + (size_t)b * 1048576;  // [32 tiles][256 d][128 kv]
  bf16* Ob = O + (size_t)b * S_LEN * 256;

  const int t = threadIdx.x, w = t >> 6, lane = t & 63;
  const int m31 = lane & 31, kh = lane >> 5;
  const bool prod = (w < 8);
  const float CL2 = 0.09016844005556021f;  // log2(e)/sqrt(D)

  if (t < 64) lb[t] = 0.f;

#define BARRIER() do { __builtin_amdgcn_s_barrier(); asm volatile("" ::: "memory"); } while (0)
#define PWAIT() asm volatile("s_waitcnt lgkmcnt(0)" ::: "memory")

  // ---- prologue: stage K(0),K(1) cooperatively (1024 threads x 4 chunks) ----
#pragma unroll
  for (int rep = 0; rep < 4; ++rep) {
    int c = rep * 1024 + t;  // 0..4095
    int tile = c >> 11, cc = c & 2047;
    int kr = cc >> 4, g = (cc & 15) ^ (kr & 7);
    async16(Kb + tile * 32768 + kr * 256 + g * 16, &ldsK[tile][cc * 16]);
  }
  asm volatile("s_waitcnt vmcnt(0) lgkmcnt(0)" ::: "memory");
  BARRIER();

  if (prod) {
    // ================= producer loop (waves 0-7): 33 barriers =================
    const int qg = w & 1, ks = (w >> 1) & 3;
    const int kn = ks * 32 + m31;  // kv row in K tile
    const int kx = kn & 7;
    const int px = m31 & 7;
    i32x8 qf[4];
    {
      const u8* qrow = Qb + (size_t)(qt * 64 + qg * 32 + m31) * 256 + kh * 32;
#pragma unroll
      for (int b2 = 0; b2 < 4; ++b2) qf[b2] = *(const i32x8*)(qrow + b2 * 64);
    }
    float l_w = 0.f;
    const int cb = (ks & 1) * 4 + (ks >> 1) * 2;

#pragma unroll 1
    for (int j = 0; j < 32; ++j) {
      const u8* kb = &ldsK[j % 3][kn * 256 + kh * 128];
      f32x16 s = {};
      __builtin_amdgcn_s_setprio(1);
#pragma unroll
      for (int b2 = 0; b2 < 4; ++b2) {
        i32x4 clo = *(const i32x4*)(kb + (((2 * b2) ^ kx) << 4));
        i32x4 chi = *(const i32x4*)(kb + (((2 * b2 + 1) ^ kx) << 4));
        s = mfma_mx(cat8(clo, chi), qf[b2], s);
      }
      __builtin_amdgcn_s_setprio(0);
      // P row = q (m31), 128B kv (permc128 order), chunk-XOR ^px.
      // kv = ks*32 + 8*g2 + 4*kh + {0..3}: chunk = cb + (g2>>1), intra = (g2&1)*8 + 4*kh.
      u8* pst = &ldsP[j & 1][qg * 4096 + m31 * 128 + 4 * kh];
#pragma unroll
      for (int g2 = 0; g2 < 4; ++g2) {
        float p0 = __builtin_amdgcn_exp2f(s[4 * g2] * CL2);
        float p1 = __builtin_amdgcn_exp2f(s[4 * g2 + 1] * CL2);
        float p2 = __builtin_amdgcn_exp2f(s[4 * g2 + 2] * CL2);
        float p3 = __builtin_amdgcn_exp2f(s[4 * g2 + 3] * CL2);
        l_w += (p0 + p1) + (p2 + p3);
        int pk = __builtin_amdgcn_cvt_pk_fp8_f32(p0, p1, 0, false);
        pk = __builtin_amdgcn_cvt_pk_fp8_f32(p2, p3, pk, true);
        *(u32*)(pst + (((cb + (g2 >> 1)) ^ px) << 4) + ((g2 & 1) << 3)) = (u32)pk;
      }
      PWAIT();
      BARRIER();
    }
    // l: fold kh halves, one shared atomicAdd per (qg,q) per wave
    l_w += __shfl_xor(l_w, 32, 64);
    if (kh == 0) atomicAdd(&lb[qg * 32 + m31], l_w);
    PWAIT();
    BARRIER();  // barrier #33: lb visible to consumers
  } else {
    // ================= consumer loop (waves 8-15): 33 barriers =================
    const int cw = w - 8;
    const int cqg = cw & 1, dpair = cw >> 1;  // dpair 0..3
    const int vd0 = dpair * 64 + m31;         // V^T d-row
    const int ct = (t - 512) & 511;           // consumer linear id 0..511
    const int px = m31 & 7;
    f32x16 o0 = {}, o1 = {};
    i32x4 vA[8];

    auto STAGE = [&](int m) {  // stage K tile m into ring slot m%3
      const u8* kg = Kb + (size_t)m * 32768;
      u8* kd = ldsK[m % 3];
#pragma unroll
      for (int jj = 0; jj < 4; ++jj) {
        int c = jj * 512 + ct;
        int kr = c >> 4, g = (c & 15) ^ (kr & 7);
        async16(kg + kr * 256 + g * 16, kd + c * 16);
      }
    };
    auto CONSV = [&](int m) {  // V tile m -> vA (128B/lane)
      const u8* vt = Vb + (size_t)m * 32768 + (size_t)vd0 * 128 + kh * 64;
      vA[0] = *(const i32x4*)(vt);
      vA[1] = *(const i32x4*)(vt + 16);
      vA[2] = *(const i32x4*)(vt + 32);
      vA[3] = *(const i32x4*)(vt + 48);
      vA[4] = *(const i32x4*)(vt + 4096);
      vA[5] = *(const i32x4*)(vt + 4112);
      vA[6] = *(const i32x4*)(vt + 4128);
      vA[7] = *(const i32x4*)(vt + 4144);
    };
    auto PV = [&](int i) {  // O += P(i) * V(i) (V in vA)
      const u8* pr = &ldsP[i & 1][cqg * 4096 + m31 * 128];
      __builtin_amdgcn_s_setprio(1);
#pragma unroll
      for (int b2 = 0; b2 < 2; ++b2) {
        const int ca = 4 * kh + 2 * b2;
        i32x4 plo = *(const i32x4*)(pr + ((ca ^ px) << 4));
        i32x4 phi = *(const i32x4*)(pr + (((ca + 1) ^ px) << 4));
        i32x8 pa = cat8(plo, phi);
        o0 = mfma_mx(pa, cat8(vA[2 * b2], vA[2 * b2 + 1]), o0);
        o1 = mfma_mx(pa, cat8(vA[4 + 2 * b2], vA[5 + 2 * b2]), o1);
      }
      __builtin_amdgcn_s_setprio(0);
    };

    // j = 0
    STAGE(2);
    CONSV(0);
    BARRIER();
    // j = 1..29
#pragma unroll 1
    for (int j = 1; j <= 29; ++j) {
      STAGE(j + 2);
      PV(j - 1);
      CONSV(j);
      BARRIER();
    }
    // j = 30, 31 (no more staging)
    PV(29);
    CONSV(30);
    BARRIER();
    PV(30);
    CONSV(31);
    BARRIER();
    PV(31);
    BARRIER();  // barrier #33: wait for producers' lb

    bf16* ob = Ob + (size_t)(qt * 64 + cqg * 32) * 256 + dpair * 64;
#pragma unroll
    for (int reg = 0; reg < 16; ++reg) {
      const int row = (reg & 3) + 8 * (reg >> 2) + 4 * kh;
      float li = lb[cqg * 32 + row];
      ob[(size_t)row * 256 + m31] = (bf16)(o0[reg] / li);
      ob[(size_t)row * 256 + 32 + m31] = (bf16)(o1[reg] / li);
    }
  }
#undef BARRIER
#undef PWAIT
}

// ---------------- gate: mean over S then dot Wg + sigmoid ----------------
__global__ __launch_bounds__(256) void gate_partial(const bf16* __restrict__ h,
                                                    float* __restrict__ part) {
  int bb = blockIdx.y;
  const bf16* hb = h + (size_t)bb * S_LEN * 256 + (size_t)blockIdx.x * 64 * 256;
  int t = threadIdx.x;
  float acc = 0.f;
#pragma unroll 4
  for (int s = 0; s < 64; ++s) acc += (float)hb[s * 256 + t];
  part[((size_t)bb * 64 + blockIdx.x) * 256 + t] = acc;
}

__global__ __launch_bounds__(256) void gate_final(const float* __restrict__ part,
                                                  const float* __restrict__ Wg,
                                                  const float* __restrict__ bg,
                                                  float* __restrict__ pg) {
  int bb = blockIdx.x, t = threadIdx.x;
  const float* p = part + (size_t)bb * 64 * 256;
  float acc = 0.f;
#pragma unroll 4
  for (int c = 0; c < 64; ++c) acc += p[c * 256 + t];
  acc *= Wg[t] * (1.0f / 4096.0f);
  __shared__ float red[256];
  red[t] = acc;
  __syncthreads();
  if (t < 64) {
    float a = red[t] + red[t + 64] + red[t + 128] + red[t + 192];
#pragma unroll
    for (int d = 1; d < 64; d <<= 1) a += __shfl_xor(a, d, 64);
    if (t == 0) pg[bb] = 1.0f / (1.0f + __expf(-(a + bg[0])));
  }
}

// ---------------- fused reparam + ELU + residual + LayerNorm ----------------
__global__ __launch_bounds__(256) void epilogue_kernel(const float* __restrict__ x,
                                                       const float* __restrict__ eps,
                                                       const float* __restrict__ mu,
                                                       const float* __restrict__ lv,
                                                       const float* __restrict__ gamma,
                                                       const float* __restrict__ beta,
                                                       float* __restrict__ out) {
  size_t base = (size_t)blockIdx.x * 1024 + (threadIdx.x >> 6) * 256;
  int l = threadIdx.x & 63;
  f32x4 xv = ((const f32x4*)(x + base))[l];
  f32x4 ev = ((const f32x4*)(eps + base))[l];
  f32x4 mv = ((const f32x4*)(mu + base))[l];
  f32x4 vv = ((const f32x4*)(lv + base))[l];
  f32x4 y;
  float s = 0.f, s2 = 0.f;
#pragma unroll
  for (int c = 0; c < 4; ++c) {
    float z = mv[c] + ev[c] * __expf(0.5f * vv[c]);
    z = z > 0.f ? z : (__expf(z) - 1.f);
    float yy = xv[c] + z;
    y[c] = yy;
    s += yy;
    s2 += yy * yy;
  }
#pragma unroll
  for (int d = 1; d < 64; d <<= 1) {
    s += __shfl_xor(s, d, 64);
    s2 += __shfl_xor(s2, d, 64);
  }
  float mean = s * (1.f / 256.f);
  float var = s2 * (1.f / 256.f) - mean * mean;
  float rstd = rsqrtf(var + 1e-5f);
  f32x4 gv = ((const f32x4*)gamma)[l];
  f32x4 bv = ((const f32x4*)beta)[l];
  f32x4 o;
#pragma unroll
  for (int c = 0; c < 4; ++c) o[c] = (y[c] - mean) * rstd * gv[c] + bv[c];
  ((f32x4*)(out + base))[l] = o;
}

// ---------------- launch ----------------
extern "C" void kernel_launch(void* const* d_in, const int* in_sizes, int n_in, void* d_out,
                              int out_size, void* d_ws, size_t ws_size, hipStream_t stream) {
  const float* x = (const float*)d_in[0];
  const float* eps = (const float*)d_in[1];
  const float* Wg = (const float*)d_in[18];
  const float* bg = (const float*)d_in[19];
  const float* gamma = (const float*)d_in[20];
  const float* beta = (const float*)d_in[21];

  char* ws = (char*)d_ws;
  bf16* x16 = (bf16*)(ws);                  // 8 MB
  bf16* h16 = (bf16*)(ws + 8388608);        // 8 MB
  u8* q8 = (u8*)(ws + 25165824);            // 4 MB
  u8* k8 = (u8*)(ws + 29360128);            // 4 MB
  u8* vt8 = (u8*)(ws + 33554432);           // 4 MB (V^T fp8 tile-major)
  bf16* w16 = (bf16*)(ws + 37748736);       // 1 MB (8 x 256x256 bf16)
  float* gpart = (float*)(ws + 38797312);   // 256 KB

  float* out = (float*)d_out;
  float* mu = out + 4194304;
  float* lv = out + 8388608;
  float* pg = out + 12582912;

  WPtrs wp;
  for (int i = 0; i < 8; ++i) wp.p[i] = (const float*)d_in[2 + i];
  cast_all_kernel<<<4608, 256, 0, stream>>>((const f32x4*)x, wp, (ushort4*)x16, (ushort4*)w16);

  GemmIO io1;
  io1.bias[0] = (const float*)d_in[10];
  io1.bias[1] = (const float*)d_in[11];
  io1.bias[2] = (const float*)d_in[12];
  io1.out[0] = q8; io1.out[1] = k8; io1.out[2] = vt8;
  gemm_qkv_kernel<<<dim3(128, 2, 3), 256, 0, stream>>>(x16, w16, io1);
  flash_kernel<<<256, 1024, 0, stream>>>(q8, k8, vt8, h16);

  GemmIO io2;
  io2.bias[0] = (const float*)d_in[13];
  io2.bias[1] = (const float*)d_in[14];
  io2.bias[2] = (const float*)d_in[15];
  io2.out[0] = q8; io2.out[1] = k8; io2.out[2] = vt8;
  gemm_qkv_kernel<<<dim3(128, 2, 3), 256, 0, stream>>>(h16, w16 + 3 * 65536, io2);
  flash_kernel<<<256, 1024, 0, stream>>>(q8, k8, vt8, h16);

  GemmIO io3;
  io3.bias[0] = (const float*)d_in[16];
  io3.bias[1] = (const float*)d_in[17];
  io3.bias[2] = nullptr;
  io3.out[0] = mu; io3.out[1] = lv; io3.out[2] = nullptr;
  gemm_f_kernel<<<dim3(128, 2, 2), 256, 0, stream>>>(h16, w16 + 6 * 65536, io3);

  gate_partial<<<dim3(64, 4), 256, 0, stream>>>(h16, gpart);
  gate_final<<<4, 256, 0, stream>>>(gpart, Wg, bg, pg);
  epilogue_kernel<<<4096, 256, 0, stream>>>(x, eps, mu, lv, gamma, beta, out);
}

// Round 12
// 279.991 us; speedup vs baseline: 1.7698x; 1.1873x over previous
//
#include <hip/hip_runtime.h>
#include <hip/hip_bf16.h>
#include <hip/hip_fp8.h>
#include <cstdint>
#include <cstddef>

// Problem: B=4, S=4096, D=256 two-layer full attention + VAE head. fp32 I/O.
// Strategy v19: flash = round-2 v12 kernel verbatim (measured 54.8us/dispatch,
// best of 6 flash designs tried) adapted to tile-major V^T source; GEMM z=2
// writes V^T fp8 tile-major via LDS-staged COALESCED stores (fixes the
// scattered byte-write path that kept non-flash time at ~170us after the
// transpose kernels were removed).

#define S_LEN 4096
#define DMODEL 256
#define NBATCH 4

typedef __bf16 bf16;
typedef __bf16 bf16x8 __attribute__((ext_vector_type(8)));
typedef float f32x4 __attribute__((ext_vector_type(4)));
typedef float f32x16 __attribute__((ext_vector_type(16)));
typedef int i32x4 __attribute__((ext_vector_type(4)));
typedef int i32x8 __attribute__((ext_vector_type(8)));
typedef unsigned char u8;
typedef unsigned int u32;

__device__ __forceinline__ f32x4 mfma16(bf16x8 a, bf16x8 b, f32x4 c) {
  return __builtin_amdgcn_mfma_f32_16x16x32_bf16(a, b, c, 0, 0, 0);
}
// MX-scaled fp8 MFMA, K=64, unit scales (e8m0 0x7F = 2^0): plain fp8 matmul at 2x rate.
__device__ __forceinline__ f32x16 mfma_mx(i32x8 a, i32x8 b, f32x16 c) {
  return __builtin_amdgcn_mfma_scale_f32_32x32x64_f8f6f4(
      a, b, c, 0, 0, 0, 0x7F7F7F7F, 0, 0x7F7F7F7F);
}
__device__ __forceinline__ i32x8 cat8(i32x4 a, i32x4 b) {
  return __builtin_shufflevector(a, b, 0, 1, 2, 3, 4, 5, 6, 7);
}

// Async global->LDS, 16B per lane. LDS dest: wave-uniform base + lane*16.
__device__ __forceinline__ void async16(const void* g, void* lds) {
  __builtin_amdgcn_global_load_lds(
      (const __attribute__((address_space(1))) unsigned int*)g,
      (__attribute__((address_space(3))) unsigned int*)lds, 16, 0, 0);
}

__device__ __forceinline__ unsigned short f2bfbits(float f) {
  return __builtin_bit_cast(unsigned short, (bf16)f);
}
__device__ __forceinline__ u8 f2fp8(float f) {
  __hip_fp8_e4m3 t(f);  // OCP e4m3fn
  return *(u8*)&t;
}
// half-split column permutation over 256-wide d for K=64 scaled MFMA:
// k = b2*64 + h*32 + m -> position h*128 + b2*32 + m.
__device__ __forceinline__ int permc(int v) {
  return (((v >> 5) & 1) << 7) + (((v >> 6) & 3) << 5) + (v & 31);
}
// same over a 128-wide dim: k = b2*64 + h*32 + m -> h*64 + b2*32 + m.
__device__ __forceinline__ int permc128(int v) {
  return (((v >> 5) & 1) << 6) + (((v >> 6) & 1) << 5) + (v & 31);
}

// ---------------- cast kernel (x + 8 weight mats in one launch) ----------------
struct WPtrs { const float* p[8]; };

__global__ void cast_all_kernel(const f32x4* __restrict__ x, WPtrs wp,
                                ushort4* __restrict__ x16, ushort4* __restrict__ w16) {
  int bx = blockIdx.x, t = threadIdx.x;
  const f32x4* src;
  ushort4* dst;
  if (bx < 4096) {
    src = x + (size_t)bx * 256 + t;
    dst = x16 + (size_t)bx * 256 + t;
  } else {
    int r = bx - 4096;
    int m = r >> 6;
    int i = (r & 63) * 256 + t;
    src = (const f32x4*)wp.p[m] + i;
    dst = w16 + (size_t)m * 16384 + i;
  }
  f32x4 v = *src;
  ushort4 o;
  o.x = f2bfbits(v[0]); o.y = f2bfbits(v[1]); o.z = f2bfbits(v[2]); o.w = f2bfbits(v[3]);
  *dst = o;
}

// ---------------- GEMM: out[m][n] = sum_k A[m][k]*W[n][k] + bias[n] ----------------
// z=0: Q fp8 (plain [M][256]); z=1: K fp8 (permc cols, [M][256]);
// z=2: V fp8 transposed tile-major [B][S/128][256 d][128 kv permc128],
//      written COALESCED via a 16KB LDS staging tile (reuses ldsA).
struct GemmIO {
  const float* bias[3];
  void* out[3];
};

__global__ __launch_bounds__(256, 3) void gemm_qkv_kernel(const bf16* __restrict__ A,
                                                          const bf16* __restrict__ Wb,
                                                          GemmIO io) {
  __shared__ __align__(16) bf16 ldsA[128 * 64];
  __shared__ __align__(16) bf16 ldsB[128 * 64];
  const int t = threadIdx.x;
  const int m0 = blockIdx.x * 128;
  const int n0 = blockIdx.y * 128;
  const bf16* W = Wb + (size_t)blockIdx.z * 65536;
  const int w = t >> 6, l = t & 63, lm = l & 15, q = l >> 4;
  const int wr = (w >> 1) * 64, wc = (w & 1) * 64;

  f32x4 acc[4][4] = {};
#pragma unroll 1
  for (int it = 0; it < 4; ++it) {
    const int k0 = it * 64;
#pragma unroll
    for (int c = 0; c < 4; ++c) {
      int i = c * 256 + t;
      int r = i >> 3, c8 = (i & 7) ^ (r & 7);
      async16(A + (size_t)(m0 + r) * 256 + k0 + c8 * 8, &ldsA[i * 8]);
    }
#pragma unroll
    for (int c = 0; c < 4; ++c) {
      int i = c * 256 + t;
      int r = i >> 3, c8 = (i & 7) ^ (r & 7);
      async16(W + (size_t)(n0 + r) * 256 + k0 + c8 * 8, &ldsB[i * 8]);
    }
    __syncthreads();
#pragma unroll
    for (int ks = 0; ks < 2; ++ks) {
      bf16x8 af[4], bfr[4];
#pragma unroll
      for (int i = 0; i < 4; ++i) {
        int ra = wr + i * 16 + lm;
        af[i] = *(const bf16x8*)&ldsA[ra * 64 + ((((ks << 2) + q) ^ (ra & 7)) << 3)];
        int rb = wc + i * 16 + lm;
        bfr[i] = *(const bf16x8*)&ldsB[rb * 64 + ((((ks << 2) + q) ^ (rb & 7)) << 3)];
      }
#pragma unroll
      for (int i = 0; i < 4; ++i)
#pragma unroll
        for (int jj = 0; jj < 4; ++jj) acc[i][jj] = mfma16(af[i], bfr[jj], acc[i][jj]);
    }
    __syncthreads();
  }
  const float* bias = io.bias[blockIdx.z];
  if (blockIdx.z == 2) {
    // Stage fp8 V^T tile [128 d][128 kv permc128] in LDS, then flat coalesced copy.
    u8* vstage = (u8*)ldsA;  // 16KB; main loop's trailing __syncthreads guarantees free
#pragma unroll
    for (int jj = 0; jj < 4; ++jj) {
      int dloc = wc + jj * 16 + lm;  // 0..127
      float bv = bias[n0 + dloc];
#pragma unroll
      for (int i = 0; i < 4; ++i) {
        int kvb = wr + i * 16 + q * 4;  // multiple of 4; permc128 keeps 4-runs contiguous
        u32 word = (u32)f2fp8(acc[i][jj][0] + bv) | ((u32)f2fp8(acc[i][jj][1] + bv) << 8) |
                   ((u32)f2fp8(acc[i][jj][2] + bv) << 16) | ((u32)f2fp8(acc[i][jj][3] + bv) << 24);
        *(u32*)&vstage[dloc * 128 + permc128(kvb)] = word;
      }
    }
    __syncthreads();
    // tile-major flat copy: 16KB block = [256 d rows from n0..n0+127][128 kv]
    int gtile = (m0 >> 12) * 32 + ((m0 & 4095) >> 7);
    u8* outb = (u8*)io.out[2] + ((size_t)gtile * 256 + n0) * 128;
#pragma unroll
    for (int cidx = 0; cidx < 4; ++cidx) {
      int c = cidx * 256 + t;  // 0..1023 chunks of 16B
      ((i32x4*)outb)[c] = ((const i32x4*)vstage)[c];
    }
  } else {
    u8* out = (u8*)io.out[blockIdx.z];
#pragma unroll
    for (int jj = 0; jj < 4; ++jj) {
      int col = n0 + wc + jj * 16 + lm;
      int scol = (blockIdx.z == 1) ? permc(col) : col;  // K gets half-split cols
      float bv = bias[col];
#pragma unroll
      for (int i = 0; i < 4; ++i) {
        int row = m0 + wr + i * 16 + q * 4;
#pragma unroll
        for (int r = 0; r < 4; ++r)
          out[(size_t)(row + r) * 256 + scol] = f2fp8(acc[i][jj][r] + bv);
      }
    }
  }
}

// mu/lv GEMM (fp32 out) — same structure.
__global__ __launch_bounds__(256, 3) void gemm_f_kernel(const bf16* __restrict__ A,
                                                        const bf16* __restrict__ Wb, GemmIO io) {
  __shared__ bf16 ldsA[128 * 64];
  __shared__ bf16 ldsB[128 * 64];
  const int t = threadIdx.x;
  const int m0 = blockIdx.x * 128;
  const int n0 = blockIdx.y * 128;
  const bf16* W = Wb + (size_t)blockIdx.z * 65536;
  const int w = t >> 6, l = t & 63, lm = l & 15, q = l >> 4;
  const int wr = (w >> 1) * 64, wc = (w & 1) * 64;

  f32x4 acc[4][4] = {};
#pragma unroll 1
  for (int it = 0; it < 4; ++it) {
    const int k0 = it * 64;
#pragma unroll
    for (int c = 0; c < 4; ++c) {
      int i = c * 256 + t;
      int r = i >> 3, c8 = (i & 7) ^ (r & 7);
      async16(A + (size_t)(m0 + r) * 256 + k0 + c8 * 8, &ldsA[i * 8]);
    }
#pragma unroll
    for (int c = 0; c < 4; ++c) {
      int i = c * 256 + t;
      int r = i >> 3, c8 = (i & 7) ^ (r & 7);
      async16(W + (size_t)(n0 + r) * 256 + k0 + c8 * 8, &ldsB[i * 8]);
    }
    __syncthreads();
#pragma unroll
    for (int ks = 0; ks < 2; ++ks) {
      bf16x8 af[4], bfr[4];
#pragma unroll
      for (int i = 0; i < 4; ++i) {
        int ra = wr + i * 16 + lm;
        af[i] = *(const bf16x8*)&ldsA[ra * 64 + ((((ks << 2) + q) ^ (ra & 7)) << 3)];
        int rb = wc + i * 16 + lm;
        bfr[i] = *(const bf16x8*)&ldsB[rb * 64 + ((((ks << 2) + q) ^ (rb & 7)) << 3)];
      }
#pragma unroll
      for (int i = 0; i < 4; ++i)
#pragma unroll
        for (int jj = 0; jj < 4; ++jj) acc[i][jj] = mfma16(af[i], bfr[jj], acc[i][jj]);
    }
    __syncthreads();
  }
  const float* bias = io.bias[blockIdx.z];
  float* out = (float*)io.out[blockIdx.z];
#pragma unroll
  for (int jj = 0; jj < 4; ++jj) {
    int col = n0 + wc + jj * 16 + lm;
    float bv = bias[col];
#pragma unroll
    for (int i = 0; i < 4; ++i) {
      int row = m0 + wr + i * 16 + q * 4;
#pragma unroll
      for (int r = 0; r < 4; ++r)
        out[(size_t)(row + r) * 256 + col] = acc[i][jj][r] + bv;
    }
  }
}

// ---------------- flash attention v19 (= round-2 v12, tile-major V source) ----------------
// 256 blocks (1/CU), 1024 threads = 16 waves. BM=64 Q rows, KV tile 128, all LDS
// tiles double-buffered (K 2x32K, V 2x32K, P 2x8K = 144KB). Waves 0-7 = producers
// (qg=w&1, ks=w>>1): QK S^T strip = mfma_mx(A=K_lds, B=Q_regs) k=256; exp in regs;
// cvt_pk_fp8 -> 4 ds_write_b32 into P[j&1]. Waves 8-15 = consumers (qg=cw&1,
// dpair=cw>>1): O strips 32q x 64d = mfma_mx(A=P[(j-1)&1], B=V[(j-1)&1]) k=128.
// One barrier per iteration; producer softmax VALU overlaps consumer MFMA.
// Measured 54.8us/dispatch (round 2; best of all flash designs this session).
__global__ __launch_bounds__(1024, 4) void flash_kernel(const u8* __restrict__ Q,
                                                        const u8* __restrict__ K,
                                                        const u8* __restrict__ Vt,
                                                        bf16* __restrict__ O) {
  __shared__ __align__(16) u8 ldsK[2][128 * 256];    // 2 x 32KB
  __shared__ __align__(16) u8 ldsV[2][256 * 128];    // 2 x 32KB
  __shared__ __align__(16) u8 ldsP[2][2 * 32 * 128]; // 2 x 8KB
  __shared__ float lb[64];

  const int id = blockIdx.x;
  const int xcd = id & 7;
  const int b = xcd >> 1;
  const int qt = (id >> 3) + ((xcd & 1) << 5);  // 0..63

  const u8* Qb = Q + (size_t)b * S_LEN * 256;
  const u8* Kb = K + (size_t)b * S_LEN * 256;
  const u8* Vb = Vt + (size_t)b * 1048576;  // tile-major [32][256 d][128 kv]
  bf16* Ob = O + (size_t)b * S_LEN * 256;

  const int t = threadIdx.x, w = t >> 6, lane = t & 63;
  const int m31 = lane & 31, kh = lane >> 5;
  const bool prod = (w < 8);
  const float CL2 = 0.09016844005556021f;  // log2(e)/sqrt(D)

  if (t < 64) lb[t] = 0.f;

  // staging: per tile 2048 16B chunks; each thread stages 2 K + 2 V chunks.
  // slot s of row r holds chunk s^(r&7) (K: 16 chunks/row; V: 8 chunks/row).
  int kld[2], kgo[2], vld[2], vgo[2];
#pragma unroll
  for (int it = 0; it < 2; ++it) {
    int c = it * 1024 + t;
    kld[it] = c * 16;
    int kr = c >> 4, kg2 = (c & 15) ^ (kr & 7);
    kgo[it] = kr * 256 + kg2 * 16;
    vld[it] = c * 16;
    int vr = c >> 3, vg2 = (c & 7) ^ (vr & 7);
    vgo[it] = vr * 128 + vg2 * 16;  // tile-major: d-row vr, 128B rows
  }

  // producer setup
  const int qg = w & 1, ks = (w >> 1) & 3;
  const int kn = ks * 32 + m31;  // local kv row in K tile
  const int kx = kn & 7;
  const int px = m31 & 7;
  i32x8 qf[4];
  if (prod) {
    const u8* qrow = Qb + (size_t)(qt * 64 + qg * 32 + m31) * 256 + kh * 32;
#pragma unroll
    for (int b2 = 0; b2 < 4; ++b2) qf[b2] = *(const i32x8*)(qrow + b2 * 64);
  }
  // consumer setup
  const int cw = w - 8;
  const int cqg = cw & 1, dpair = cw >> 1;  // dpair 0..3
  const int vd0 = dpair * 64 + m31;
  const int vx = vd0 & 7;  // (vd0+32)&7 identical

  f32x16 o0 = {}, o1 = {};
  float l_w = 0.f;

  // prologue: stage K(0) into buf 0, then drain
#pragma unroll
  for (int it = 0; it < 2; ++it) async16(Kb + kgo[it], &ldsK[0][kld[it]]);
  __syncthreads();

#pragma unroll 1
  for (int j = 0; j <= 32; ++j) {
    if (j < 32) {  // stage V(j) -> Vbuf[j&1] (consumed at j+1)
      const u8* vg = Vb + (size_t)j * 32768;
#pragma unroll
      for (int it = 0; it < 2; ++it) async16(vg + vgo[it], &ldsV[j & 1][vld[it]]);
    }
    if (j < 31) {  // stage K(j+1) -> Kbuf[(j+1)&1]
      const u8* kg = Kb + (size_t)(j + 1) * 128 * 256;
#pragma unroll
      for (int it = 0; it < 2; ++it) async16(kg + kgo[it], &ldsK[(j + 1) & 1][kld[it]]);
    }
    if (prod) {
      if (j < 32) {
        const u8* kb = &ldsK[j & 1][kn * 256 + kh * 128];
        f32x16 s = {};
        __builtin_amdgcn_s_setprio(1);
#pragma unroll
        for (int b2 = 0; b2 < 4; ++b2) {
          i32x4 klo = *(const i32x4*)(kb + (((2 * b2) ^ kx) << 4));
          i32x4 khi = *(const i32x4*)(kb + (((2 * b2 + 1) ^ kx) << 4));
          s = mfma_mx(cat8(klo, khi), qf[b2], s);
        }
        __builtin_amdgcn_s_setprio(0);
        float p[16];
#pragma unroll
        for (int r = 0; r < 16; ++r) {
          p[r] = __builtin_amdgcn_exp2f(s[r] * CL2);
          l_w += p[r];
        }
        // P row = q (m31), 128B of kv (permc128 order), chunk-XOR ^px.
        // kv = ks*32 + 8*g2 + 4*kh + {0..3}: chunk = (ks&1)*4+(ks>>1)*2+(g2>>1),
        // intra = (g2&1)*8 + 4*kh.
        u8* pst = &ldsP[j & 1][qg * 4096 + m31 * 128 + 4 * kh];
        const int cb = (ks & 1) * 4 + (ks >> 1) * 2;
#pragma unroll
        for (int g2 = 0; g2 < 4; ++g2) {
          int pk = __builtin_amdgcn_cvt_pk_fp8_f32(p[4 * g2], p[4 * g2 + 1], 0, false);
          pk = __builtin_amdgcn_cvt_pk_fp8_f32(p[4 * g2 + 2], p[4 * g2 + 3], pk, true);
          *(u32*)(pst + (((cb + (g2 >> 1)) ^ px) << 4) + ((g2 & 1) << 3)) = (u32)pk;
        }
      }
    } else {
      if (j > 0) {
        const int pb = (j - 1) & 1;
        const u8* pr = &ldsP[pb][cqg * 4096 + m31 * 128];
        const u8* v0 = &ldsV[pb][(size_t)vd0 * 128];
        const u8* v1 = v0 + 32 * 128;
        __builtin_amdgcn_s_setprio(1);
#pragma unroll
        for (int b2 = 0; b2 < 2; ++b2) {
          const int ca = 4 * kh + 2 * b2;
          i32x4 plo = *(const i32x4*)(pr + ((ca ^ px) << 4));
          i32x4 phi = *(const i32x4*)(pr + (((ca + 1) ^ px) << 4));
          i32x8 pa = cat8(plo, phi);
          i32x4 va = *(const i32x4*)(v0 + ((ca ^ vx) << 4));
          i32x4 vb2 = *(const i32x4*)(v0 + (((ca + 1) ^ vx) << 4));
          o0 = mfma_mx(pa, cat8(va, vb2), o0);
          i32x4 vc = *(const i32x4*)(v1 + ((ca ^ vx) << 4));
          i32x4 vd2 = *(const i32x4*)(v1 + (((ca + 1) ^ vx) << 4));
          o1 = mfma_mx(pa, cat8(vc, vd2), o1);
        }
        __builtin_amdgcn_s_setprio(0);
      }
    }
    __syncthreads();
  }

  // l: fold kh halves, one shared atomicAdd per (qg,q) per producer wave
  if (prod) {
    l_w += __shfl_xor(l_w, 32, 64);
    if (kh == 0) atomicAdd(&lb[qg * 32 + m31], l_w);
  }
  __syncthreads();

  if (!prod) {
    bf16* ob0 = Ob + (size_t)(qt * 64 + cqg * 32) * 256 + dpair * 64;
#pragma unroll
    for (int reg = 0; reg < 16; ++reg) {
      const int row = (reg & 3) + 8 * (reg >> 2) + 4 * kh;
      float li = lb[cqg * 32 + row];
      ob0[(size_t)row * 256 + m31] = (bf16)(o0[reg] / li);
      ob0[(size_t)row * 256 + 32 + m31] = (bf16)(o1[reg] / li);
    }
  }
}

// ---------------- gate: mean over S then dot Wg + sigmoid ----------------
__global__ __launch_bounds__(256) void gate_partial(const bf16* __restrict__ h,
                                                    float* __restrict__ part) {
  int bb = blockIdx.y;
  const bf16* hb = h + (size_t)bb * S_LEN * 256 + (size_t)blockIdx.x * 64 * 256;
  int t = threadIdx.x;
  float acc = 0.f;
#pragma unroll 4
  for (int s = 0; s < 64; ++s) acc += (float)hb[s * 256 + t];
  part[((size_t)bb * 64 + blockIdx.x) * 256 + t] = acc;
}

__global__ __launch_bounds__(256) void gate_final(const float* __restrict__ part,
                                                  const float* __restrict__ Wg,
                                                  const float* __restrict__ bg,
                                                  float* __restrict__ pg) {
  int bb = blockIdx.x, t = threadIdx.x;
  const float* p = part + (size_t)bb * 64 * 256;
  float acc = 0.f;
#pragma unroll 4
  for (int c = 0; c < 64; ++c) acc += p[c * 256 + t];
  acc *= Wg[t] * (1.0f / 4096.0f);
  __shared__ float red[256];
  red[t] = acc;
  __syncthreads();
  if (t < 64) {
    float a = red[t] + red[t + 64] + red[t + 128] + red[t + 192];
#pragma unroll
    for (int d = 1; d < 64; d <<= 1) a += __shfl_xor(a, d, 64);
    if (t == 0) pg[bb] = 1.0f / (1.0f + __expf(-(a + bg[0])));
  }
}

// ---------------- fused reparam + ELU + residual + LayerNorm ----------------
__global__ __launch_bounds__(256) void epilogue_kernel(const float* __restrict__ x,
                                                       const float* __restrict__ eps,
                                                       const float* __restrict__ mu,
                                                       const float* __restrict__ lv,
                                                       const float* __restrict__ gamma,
                                                       const float* __restrict__ beta,
                                                       float* __restrict__ out) {
  size_t base = (size_t)blockIdx.x * 1024 + (threadIdx.x >> 6) * 256;
  int l = threadIdx.x & 63;
  f32x4 xv = ((const f32x4*)(x + base))[l];
  f32x4 ev = ((const f32x4*)(eps + base))[l];
  f32x4 mv = ((const f32x4*)(mu + base))[l];
  f32x4 vv = ((const f32x4*)(lv + base))[l];
  f32x4 y;
  float s = 0.f, s2 = 0.f;
#pragma unroll
  for (int c = 0; c < 4; ++c) {
    float z = mv[c] + ev[c] * __expf(0.5f * vv[c]);
    z = z > 0.f ? z : (__expf(z) - 1.f);
    float yy = xv[c] + z;
    y[c] = yy;
    s += yy;
    s2 += yy * yy;
  }
#pragma unroll
  for (int d = 1; d < 64; d <<= 1) {
    s += __shfl_xor(s, d, 64);
    s2 += __shfl_xor(s2, d, 64);
  }
  float mean = s * (1.f / 256.f);
  float var = s2 * (1.f / 256.f) - mean * mean;
  float rstd = rsqrtf(var + 1e-5f);
  f32x4 gv = ((const f32x4*)gamma)[l];
  f32x4 bv = ((const f32x4*)beta)[l];
  f32x4 o;
#pragma unroll
  for (int c = 0; c < 4; ++c) o[c] = (y[c] - mean) * rstd * gv[c] + bv[c];
  ((f32x4*)(out + base))[l] = o;
}

// ---------------- launch ----------------
extern "C" void kernel_launch(void* const* d_in, const int* in_sizes, int n_in, void* d_out,
                              int out_size, void* d_ws, size_t ws_size, hipStream_t stream) {
  const float* x = (const float*)d_in[0];
  const float* eps = (const float*)d_in[1];
  const float* Wg = (const float*)d_in[18];
  const float* bg = (const float*)d_in[19];
  const float* gamma = (const float*)d_in[20];
  const float* beta = (const float*)d_in[21];

  char* ws = (char*)d_ws;
  bf16* x16 = (bf16*)(ws);                  // 8 MB
  bf16* h16 = (bf16*)(ws + 8388608);        // 8 MB
  u8* q8 = (u8*)(ws + 25165824);            // 4 MB
  u8* k8 = (u8*)(ws + 29360128);            // 4 MB
  u8* vt8 = (u8*)(ws + 33554432);           // 4 MB (V^T fp8 tile-major)
  bf16* w16 = (bf16*)(ws + 37748736);       // 1 MB (8 x 256x256 bf16)
  float* gpart = (float*)(ws + 38797312);   // 256 KB

  float* out = (float*)d_out;
  float* mu = out + 4194304;
  float* lv = out + 8388608;
  float* pg = out + 12582912;

  WPtrs wp;
  for (int i = 0; i < 8; ++i) wp.p[i] = (const float*)d_in[2 + i];
  cast_all_kernel<<<4608, 256, 0, stream>>>((const f32x4*)x, wp, (ushort4*)x16, (ushort4*)w16);

  GemmIO io1;
  io1.bias[0] = (const float*)d_in[10];
  io1.bias[1] = (const float*)d_in[11];
  io1.bias[2] = (const float*)d_in[12];
  io1.out[0] = q8; io1.out[1] = k8; io1.out[2] = vt8;
  gemm_qkv_kernel<<<dim3(128, 2, 3), 256, 0, stream>>>(x16, w16, io1);
  flash_kernel<<<256, 1024, 0, stream>>>(q8, k8, vt8, h16);

  GemmIO io2;
  io2.bias[0] = (const float*)d_in[13];
  io2.bias[1] = (const float*)d_in[14];
  io2.bias[2] = (const float*)d_in[15];
  io2.out[0] = q8; io2.out[1] = k8; io2.out[2] = vt8;
  gemm_qkv_kernel<<<dim3(128, 2, 3), 256, 0, stream>>>(h16, w16 + 3 * 65536, io2);
  flash_kernel<<<256, 1024, 0, stream>>>(q8, k8, vt8, h16);

  GemmIO io3;
  io3.bias[0] = (const float*)d_in[16];
  io3.bias[1] = (const float*)d_in[17];
  io3.bias[2] = nullptr;
  io3.out[0] = mu; io3.out[1] = lv; io3.out[2] = nullptr;
  gemm_f_kernel<<<dim3(128, 2, 2), 256, 0, stream>>>(h16, w16 + 6 * 65536, io3);

  gate_partial<<<dim3(64, 4), 256, 0, stream>>>(h16, gpart);
  gate_final<<<4, 256, 0, stream>>>(gpart, Wg, bg, pg);
  epilogue_kernel<<<4096, 256, 0, stream>>>(x, eps, mu, lv, gamma, beta, out);
}

// Round 14
// 271.344 us; speedup vs baseline: 1.8262x; 1.0319x over previous
//
#include <hip/hip_runtime.h>
#include <hip/hip_bf16.h>
#include <hip/hip_fp8.h>
#include <cstdint>
#include <cstddef>

// Problem: B=4, S=4096, D=256 two-layer full attention + VAE head. fp32 I/O.
// Strategy v20: flash = v12/v19 kernel (measured 52.5us/dispatch, best of all
// designs this session); ALL fp8 GEMM outputs (Q, K, V^T) written via
// LDS-staged COALESCED stores (v19 fixed V; this round fixes Q/K's 16
// scattered byte-stores/thread, ~64x sector amplification).

#define S_LEN 4096
#define DMODEL 256
#define NBATCH 4

typedef __bf16 bf16;
typedef __bf16 bf16x8 __attribute__((ext_vector_type(8)));
typedef float f32x4 __attribute__((ext_vector_type(4)));
typedef float f32x16 __attribute__((ext_vector_type(16)));
typedef int i32x4 __attribute__((ext_vector_type(4)));
typedef int i32x8 __attribute__((ext_vector_type(8)));
typedef unsigned char u8;
typedef unsigned int u32;

__device__ __forceinline__ f32x4 mfma16(bf16x8 a, bf16x8 b, f32x4 c) {
  return __builtin_amdgcn_mfma_f32_16x16x32_bf16(a, b, c, 0, 0, 0);
}
// MX-scaled fp8 MFMA, K=64, unit scales (e8m0 0x7F = 2^0): plain fp8 matmul at 2x rate.
__device__ __forceinline__ f32x16 mfma_mx(i32x8 a, i32x8 b, f32x16 c) {
  return __builtin_amdgcn_mfma_scale_f32_32x32x64_f8f6f4(
      a, b, c, 0, 0, 0, 0x7F7F7F7F, 0, 0x7F7F7F7F);
}
__device__ __forceinline__ i32x8 cat8(i32x4 a, i32x4 b) {
  return __builtin_shufflevector(a, b, 0, 1, 2, 3, 4, 5, 6, 7);
}

// Async global->LDS, 16B per lane. LDS dest: wave-uniform base + lane*16.
__device__ __forceinline__ void async16(const void* g, void* lds) {
  __builtin_amdgcn_global_load_lds(
      (const __attribute__((address_space(1))) unsigned int*)g,
      (__attribute__((address_space(3))) unsigned int*)lds, 16, 0, 0);
}

__device__ __forceinline__ unsigned short f2bfbits(float f) {
  return __builtin_bit_cast(unsigned short, (bf16)f);
}
__device__ __forceinline__ u8 f2fp8(float f) {
  __hip_fp8_e4m3 t(f);  // OCP e4m3fn
  return *(u8*)&t;
}
// half-split column permutation over 256-wide d for K=64 scaled MFMA:
// k = b2*64 + h*32 + m -> position h*128 + b2*32 + m.
// Identity used in the GEMM-K epilogue: permc(n0+j) =
//   ((j>>5)&1)*128 + (n0>>7)*64 + ((j>>6)&1)*32 + (j&31)   for j in [0,128).
__device__ __forceinline__ int permc(int v) {
  return (((v >> 5) & 1) << 7) + (((v >> 6) & 3) << 5) + (v & 31);
}
// same over a 128-wide dim: k = b2*64 + h*32 + m -> h*64 + b2*32 + m.
__device__ __forceinline__ int permc128(int v) {
  return (((v >> 5) & 1) << 6) + (((v >> 6) & 1) << 5) + (v & 31);
}

// ---------------- cast kernel (x + 8 weight mats in one launch) ----------------
struct WPtrs { const float* p[8]; };

__global__ void cast_all_kernel(const f32x4* __restrict__ x, WPtrs wp,
                                ushort4* __restrict__ x16, ushort4* __restrict__ w16) {
  int bx = blockIdx.x, t = threadIdx.x;
  const f32x4* src;
  ushort4* dst;
  if (bx < 4096) {
    src = x + (size_t)bx * 256 + t;
    dst = x16 + (size_t)bx * 256 + t;
  } else {
    int r = bx - 4096;
    int m = r >> 6;
    int i = (r & 63) * 256 + t;
    src = (const f32x4*)wp.p[m] + i;
    dst = w16 + (size_t)m * 16384 + i;
  }
  f32x4 v = *src;
  ushort4 o;
  o.x = f2bfbits(v[0]); o.y = f2bfbits(v[1]); o.z = f2bfbits(v[2]); o.w = f2bfbits(v[3]);
  *dst = o;
}

// ---------------- GEMM: out[m][n] = sum_k A[m][k]*W[n][k] + bias[n] ----------------
// z=0: Q fp8 (plain [M][256]); z=1: K fp8 (permc cols, [M][256]);
// z=2: V fp8 transposed tile-major [B][S/128][256 d][128 kv permc128].
// ALL THREE epilogues stage their 16KB fp8 tile in LDS (reusing ldsA) and
// write global with coalesced 16B chunks (Q: 128B runs/row; K: 2x64B runs/row;
// V: flat 16KB block).
struct GemmIO {
  const float* bias[3];
  void* out[3];
};

__global__ __launch_bounds__(256, 3) void gemm_qkv_kernel(const bf16* __restrict__ A,
                                                          const bf16* __restrict__ Wb,
                                                          GemmIO io) {
  __shared__ __align__(16) bf16 ldsA[128 * 64];
  __shared__ __align__(16) bf16 ldsB[128 * 64];
  const int t = threadIdx.x;
  const int m0 = blockIdx.x * 128;
  const int n0 = blockIdx.y * 128;
  const bf16* W = Wb + (size_t)blockIdx.z * 65536;
  const int w = t >> 6, l = t & 63, lm = l & 15, q = l >> 4;
  const int wr = (w >> 1) * 64, wc = (w & 1) * 64;

  f32x4 acc[4][4] = {};
#pragma unroll 1
  for (int it = 0; it < 4; ++it) {
    const int k0 = it * 64;
#pragma unroll
    for (int c = 0; c < 4; ++c) {
      int i = c * 256 + t;
      int r = i >> 3, c8 = (i & 7) ^ (r & 7);
      async16(A + (size_t)(m0 + r) * 256 + k0 + c8 * 8, &ldsA[i * 8]);
    }
#pragma unroll
    for (int c = 0; c < 4; ++c) {
      int i = c * 256 + t;
      int r = i >> 3, c8 = (i & 7) ^ (r & 7);
      async16(W + (size_t)(n0 + r) * 256 + k0 + c8 * 8, &ldsB[i * 8]);
    }
    __syncthreads();
#pragma unroll
    for (int ks = 0; ks < 2; ++ks) {
      bf16x8 af[4], bfr[4];
#pragma unroll
      for (int i = 0; i < 4; ++i) {
        int ra = wr + i * 16 + lm;
        af[i] = *(const bf16x8*)&ldsA[ra * 64 + ((((ks << 2) + q) ^ (ra & 7)) << 3)];
        int rb = wc + i * 16 + lm;
        bfr[i] = *(const bf16x8*)&ldsB[rb * 64 + ((((ks << 2) + q) ^ (rb & 7)) << 3)];
      }
#pragma unroll
      for (int i = 0; i < 4; ++i)
#pragma unroll
        for (int jj = 0; jj < 4; ++jj) acc[i][jj] = mfma16(af[i], bfr[jj], acc[i][jj]);
    }
    __syncthreads();
  }
  const float* bias = io.bias[blockIdx.z];
  u8* vstage = (u8*)ldsA;  // 16KB; main loop's trailing __syncthreads guarantees free
  if (blockIdx.z == 2) {
    // V: stage fp8 V^T tile [128 d][128 kv permc128] in LDS, then flat coalesced copy.
#pragma unroll
    for (int jj = 0; jj < 4; ++jj) {
      int dloc = wc + jj * 16 + lm;  // 0..127
      float bv = bias[n0 + dloc];
#pragma unroll
      for (int i = 0; i < 4; ++i) {
        int kvb = wr + i * 16 + q * 4;  // multiple of 4; permc128 keeps 4-runs contiguous
        u32 word = (u32)f2fp8(acc[i][jj][0] + bv) | ((u32)f2fp8(acc[i][jj][1] + bv) << 8) |
                   ((u32)f2fp8(acc[i][jj][2] + bv) << 16) | ((u32)f2fp8(acc[i][jj][3] + bv) << 24);
        *(u32*)&vstage[dloc * 128 + permc128(kvb)] = word;
      }
    }
    __syncthreads();
    // tile-major flat copy: 16KB block = [128 d rows from n0..n0+127][128 kv]
    int gtile = (m0 >> 12) * 32 + ((m0 & 4095) >> 7);
    u8* outb = (u8*)io.out[2] + ((size_t)gtile * 256 + n0) * 128;
#pragma unroll
    for (int cidx = 0; cidx < 4; ++cidx) {
      int c = cidx * 256 + t;  // 0..1023 chunks of 16B
      ((i32x4*)outb)[c] = ((const i32x4*)vstage)[c];
    }
  } else {
    // Q/K: stage fp8 tile [128 rows][128 local cols] in LDS, coalesced copy out.
    // K's local col layout bakes permc: lc = ((j>>5)&1)*64 + ((j>>6)&1)*32 + (j&31);
    // global col = (lc>>6)*128 + (n0>>7)*64 + (lc&63).
    const bool isK = (blockIdx.z == 1);
#pragma unroll
    for (int jj = 0; jj < 4; ++jj) {
      int j = wc + jj * 16 + lm;  // local col 0..127
      int lc = isK ? (((j >> 5) & 1) * 64 + ((j >> 6) & 1) * 32 + (j & 31)) : j;
      float bv = bias[n0 + j];
#pragma unroll
      for (int i = 0; i < 4; ++i) {
        int rloc = wr + i * 16 + q * 4;
#pragma unroll
        for (int r = 0; r < 4; ++r)
          vstage[(rloc + r) * 128 + lc] = f2fp8(acc[i][jj][r] + bv);
      }
    }
    __syncthreads();
    u8* outz = (u8*)io.out[blockIdx.z];
    const int off = (n0 >> 7) * 64;
#pragma unroll
    for (int cidx = 0; cidx < 4; ++cidx) {
      int c = cidx * 256 + t;  // 0..1023
      int row = c >> 3, k = c & 7;
      int gcol = isK ? ((k >> 2) * 128 + off + (k & 3) * 16) : (n0 + k * 16);
      *(i32x4*)(outz + (size_t)(m0 + row) * 256 + gcol) =
          *(const i32x4*)(vstage + row * 128 + k * 16);
    }
  }
}

// mu/lv GEMM (fp32 out) — same structure.
__global__ __launch_bounds__(256, 3) void gemm_f_kernel(const bf16* __restrict__ A,
                                                        const bf16* __restrict__ Wb, GemmIO io) {
  __shared__ bf16 ldsA[128 * 64];
  __shared__ bf16 ldsB[128 * 64];
  const int t = threadIdx.x;
  const int m0 = blockIdx.x * 128;
  const int n0 = blockIdx.y * 128;
  const bf16* W = Wb + (size_t)blockIdx.z * 65536;
  const int w = t >> 6, l = t & 63, lm = l & 15, q = l >> 4;
  const int wr = (w >> 1) * 64, wc = (w & 1) * 64;

  f32x4 acc[4][4] = {};
#pragma unroll 1
  for (int it = 0; it < 4; ++it) {
    const int k0 = it * 64;
#pragma unroll
    for (int c = 0; c < 4; ++c) {
      int i = c * 256 + t;
      int r = i >> 3, c8 = (i & 7) ^ (r & 7);
      async16(A + (size_t)(m0 + r) * 256 + k0 + c8 * 8, &ldsA[i * 8]);
    }
#pragma unroll
    for (int c = 0; c < 4; ++c) {
      int i = c * 256 + t;
      int r = i >> 3, c8 = (i & 7) ^ (r & 7);
      async16(W + (size_t)(n0 + r) * 256 + k0 + c8 * 8, &ldsB[i * 8]);
    }
    __syncthreads();
#pragma unroll
    for (int ks = 0; ks < 2; ++ks) {
      bf16x8 af[4], bfr[4];
#pragma unroll
      for (int i = 0; i < 4; ++i) {
        int ra = wr + i * 16 + lm;
        af[i] = *(const bf16x8*)&ldsA[ra * 64 + ((((ks << 2) + q) ^ (ra & 7)) << 3)];
        int rb = wc + i * 16 + lm;
        bfr[i] = *(const bf16x8*)&ldsB[rb * 64 + ((((ks << 2) + q) ^ (rb & 7)) << 3)];
      }
#pragma unroll
      for (int i = 0; i < 4; ++i)
#pragma unroll
        for (int jj = 0; jj < 4; ++jj) acc[i][jj] = mfma16(af[i], bfr[jj], acc[i][jj]);
    }
    __syncthreads();
  }
  const float* bias = io.bias[blockIdx.z];
  float* out = (float*)io.out[blockIdx.z];
#pragma unroll
  for (int jj = 0; jj < 4; ++jj) {
    int col = n0 + wc + jj * 16 + lm;
    float bv = bias[col];
#pragma unroll
    for (int i = 0; i < 4; ++i) {
      int row = m0 + wr + i * 16 + q * 4;
#pragma unroll
      for (int r = 0; r < 4; ++r)
        out[(size_t)(row + r) * 256 + col] = acc[i][jj][r] + bv;
    }
  }
}

// ---------------- flash attention v20 (= v12/v19, tile-major V source) ----------------
// 256 blocks (1/CU), 1024 threads = 16 waves. BM=64 Q rows, KV tile 128, all LDS
// tiles double-buffered (K 2x32K, V 2x32K, P 2x8K = 144KB). Waves 0-7 = producers
// (qg=w&1, ks=w>>1): QK S^T strip = mfma_mx(A=K_lds, B=Q_regs) k=256; exp in regs;
// cvt_pk_fp8 -> 4 ds_write_b32 into P[j&1]. Waves 8-15 = consumers (qg=cw&1,
// dpair=cw>>1): O strips 32q x 64d = mfma_mx(A=P[(j-1)&1], B=V[(j-1)&1]) k=128.
// One barrier per iteration; producer softmax VALU overlaps consumer MFMA.
// Measured 52.5us/dispatch (round 12; best of all flash designs this session).
__global__ __launch_bounds__(1024, 4) void flash_kernel(const u8* __restrict__ Q,
                                                        const u8* __restrict__ K,
                                                        const u8* __restrict__ Vt,
                                                        bf16* __restrict__ O) {
  __shared__ __align__(16) u8 ldsK[2][128 * 256];    // 2 x 32KB
  __shared__ __align__(16) u8 ldsV[2][256 * 128];    // 2 x 32KB
  __shared__ __align__(16) u8 ldsP[2][2 * 32 * 128]; // 2 x 8KB
  __shared__ float lb[64];

  const int id = blockIdx.x;
  const int xcd = id & 7;
  const int b = xcd >> 1;
  const int qt = (id >> 3) + ((xcd & 1) << 5);  // 0..63

  const u8* Qb = Q + (size_t)b * S_LEN * 256;
  const u8* Kb = K + (size_t)b * S_LEN * 256;
  const u8* Vb = Vt + (size_t)b * 1048576;  // tile-major [32][256 d][128 kv]
  bf16* Ob = O + (size_t)b * S_LEN * 256;

  const int t = threadIdx.x, w = t >> 6, lane = t & 63;
  const int m31 = lane & 31, kh = lane >> 5;
  const bool prod = (w < 8);
  const float CL2 = 0.09016844005556021f;  // log2(e)/sqrt(D)

  if (t < 64) lb[t] = 0.f;

  // staging: per tile 2048 16B chunks; each thread stages 2 K + 2 V chunks.
  // slot s of row r holds chunk s^(r&7) (K: 16 chunks/row; V: 8 chunks/row).
  int kld[2], kgo[2], vld[2], vgo[2];
#pragma unroll
  for (int it = 0; it < 2; ++it) {
    int c = it * 1024 + t;
    kld[it] = c * 16;
    int kr = c >> 4, kg2 = (c & 15) ^ (kr & 7);
    kgo[it] = kr * 256 + kg2 * 16;
    vld[it] = c * 16;
    int vr = c >> 3, vg2 = (c & 7) ^ (vr & 7);
    vgo[it] = vr * 128 + vg2 * 16;  // tile-major: d-row vr, 128B rows
  }

  // producer setup
  const int qg = w & 1, ks = (w >> 1) & 3;
  const int kn = ks * 32 + m31;  // local kv row in K tile
  const int kx = kn & 7;
  const int px = m31 & 7;
  i32x8 qf[4];
  if (prod) {
    const u8* qrow = Qb + (size_t)(qt * 64 + qg * 32 + m31) * 256 + kh * 32;
#pragma unroll
    for (int b2 = 0; b2 < 4; ++b2) qf[b2] = *(const i32x8*)(qrow + b2 * 64);
  }
  // consumer setup
  const int cw = w - 8;
  const int cqg = cw & 1, dpair = cw >> 1;  // dpair 0..3
  const int vd0 = dpair * 64 + m31;
  const int vx = vd0 & 7;  // (vd0+32)&7 identical

  f32x16 o0 = {}, o1 = {};
  float l_w = 0.f;

  // prologue: stage K(0) into buf 0, then drain
#pragma unroll
  for (int it = 0; it < 2; ++it) async16(Kb + kgo[it], &ldsK[0][kld[it]]);
  __syncthreads();

#pragma unroll 1
  for (int j = 0; j <= 32; ++j) {
    if (j < 32) {  // stage V(j) -> Vbuf[j&1] (consumed at j+1)
      const u8* vg = Vb + (size_t)j * 32768;
#pragma unroll
      for (int it = 0; it < 2; ++it) async16(vg + vgo[it], &ldsV[j & 1][vld[it]]);
    }
    if (j < 31) {  // stage K(j+1) -> Kbuf[(j+1)&1]
      const u8* kg = Kb + (size_t)(j + 1) * 128 * 256;
#pragma unroll
      for (int it = 0; it < 2; ++it) async16(kg + kgo[it], &ldsK[(j + 1) & 1][kld[it]]);
    }
    if (prod) {
      if (j < 32) {
        const u8* kb = &ldsK[j & 1][kn * 256 + kh * 128];
        f32x16 s = {};
        __builtin_amdgcn_s_setprio(1);
#pragma unroll
        for (int b2 = 0; b2 < 4; ++b2) {
          i32x4 klo = *(const i32x4*)(kb + (((2 * b2) ^ kx) << 4));
          i32x4 khi = *(const i32x4*)(kb + (((2 * b2 + 1) ^ kx) << 4));
          s = mfma_mx(cat8(klo, khi), qf[b2], s);
        }
        __builtin_amdgcn_s_setprio(0);
        float p[16];
#pragma unroll
        for (int r = 0; r < 16; ++r) {
          p[r] = __builtin_amdgcn_exp2f(s[r] * CL2);
          l_w += p[r];
        }
        // P row = q (m31), 128B of kv (permc128 order), chunk-XOR ^px.
        // kv = ks*32 + 8*g2 + 4*kh + {0..3}: chunk = (ks&1)*4+(ks>>1)*2+(g2>>1),
        // intra = (g2&1)*8 + 4*kh.
        u8* pst = &ldsP[j & 1][qg * 4096 + m31 * 128 + 4 * kh];
        const int cb = (ks & 1) * 4 + (ks >> 1) * 2;
#pragma unroll
        for (int g2 = 0; g2 < 4; ++g2) {
          int pk = __builtin_amdgcn_cvt_pk_fp8_f32(p[4 * g2], p[4 * g2 + 1], 0, false);
          pk = __builtin_amdgcn_cvt_pk_fp8_f32(p[4 * g2 + 2], p[4 * g2 + 3], pk, true);
          *(u32*)(pst + (((cb + (g2 >> 1)) ^ px) << 4) + ((g2 & 1) << 3)) = (u32)pk;
        }
      }
    } else {
      if (j > 0) {
        const int pb = (j - 1) & 1;
        const u8* pr = &ldsP[pb][cqg * 4096 + m31 * 128];
        const u8* v0 = &ldsV[pb][(size_t)vd0 * 128];
        const u8* v1 = v0 + 32 * 128;
        __builtin_amdgcn_s_setprio(1);
#pragma unroll
        for (int b2 = 0; b2 < 2; ++b2) {
          const int ca = 4 * kh + 2 * b2;
          i32x4 plo = *(const i32x4*)(pr + ((ca ^ px) << 4));
          i32x4 phi = *(const i32x4*)(pr + (((ca + 1) ^ px) << 4));
          i32x8 pa = cat8(plo, phi);
          i32x4 va = *(const i32x4*)(v0 + ((ca ^ vx) << 4));
          i32x4 vb2 = *(const i32x4*)(v0 + (((ca + 1) ^ vx) << 4));
          o0 = mfma_mx(pa, cat8(va, vb2), o0);
          i32x4 vc = *(const i32x4*)(v1 + ((ca ^ vx) << 4));
          i32x4 vd2 = *(const i32x4*)(v1 + (((ca + 1) ^ vx) << 4));
          o1 = mfma_mx(pa, cat8(vc, vd2), o1);
        }
        __builtin_amdgcn_s_setprio(0);
      }
    }
    __syncthreads();
  }

  // l: fold kh halves, one shared atomicAdd per (qg,q) per producer wave
  if (prod) {
    l_w += __shfl_xor(l_w, 32, 64);
    if (kh == 0) atomicAdd(&lb[qg * 32 + m31], l_w);
  }
  __syncthreads();

  if (!prod) {
    bf16* ob0 = Ob + (size_t)(qt * 64 + cqg * 32) * 256 + dpair * 64;
#pragma unroll
    for (int reg = 0; reg < 16; ++reg) {
      const int row = (reg & 3) + 8 * (reg >> 2) + 4 * kh;
      float li = lb[cqg * 32 + row];
      ob0[(size_t)row * 256 + m31] = (bf16)(o0[reg] / li);
      ob0[(size_t)row * 256 + 32 + m31] = (bf16)(o1[reg] / li);
    }
  }
}

// ---------------- gate: mean over S then dot Wg + sigmoid ----------------
__global__ __launch_bounds__(256) void gate_partial(const bf16* __restrict__ h,
                                                    float* __restrict__ part) {
  int bb = blockIdx.y;
  const bf16* hb = h + (size_t)bb * S_LEN * 256 + (size_t)blockIdx.x * 64 * 256;
  int t = threadIdx.x;
  float acc = 0.f;
#pragma unroll 4
  for (int s = 0; s < 64; ++s) acc += (float)hb[s * 256 + t];
  part[((size_t)bb * 64 + blockIdx.x) * 256 + t] = acc;
}

__global__ __launch_bounds__(256) void gate_final(const float* __restrict__ part,
                                                  const float* __restrict__ Wg,
                                                  const float* __restrict__ bg,
                                                  float* __restrict__ pg) {
  int bb = blockIdx.x, t = threadIdx.x;
  const float* p = part + (size_t)bb * 64 * 256;
  float acc = 0.f;
#pragma unroll 4
  for (int c = 0; c < 64; ++c) acc += p[c * 256 + t];
  acc *= Wg[t] * (1.0f / 4096.0f);
  __shared__ float red[256];
  red[t] = acc;
  __syncthreads();
  if (t < 64) {
    float a = red[t] + red[t + 64] + red[t + 128] + red[t + 192];
#pragma unroll
    for (int d = 1; d < 64; d <<= 1) a += __shfl_xor(a, d, 64);
    if (t == 0) pg[bb] = 1.0f / (1.0f + __expf(-(a + bg[0])));
  }
}

// ---------------- fused reparam + ELU + residual + LayerNorm ----------------
__global__ __launch_bounds__(256) void epilogue_kernel(const float* __restrict__ x,
                                                       const float* __restrict__ eps,
                                                       const float* __restrict__ mu,
                                                       const float* __restrict__ lv,
                                                       const float* __restrict__ gamma,
                                                       const float* __restrict__ beta,
                                                       float* __restrict__ out) {
  size_t base = (size_t)blockIdx.x * 1024 + (threadIdx.x >> 6) * 256;
  int l = threadIdx.x & 63;
  f32x4 xv = ((const f32x4*)(x + base))[l];
  f32x4 ev = ((const f32x4*)(eps + base))[l];
  f32x4 mv = ((const f32x4*)(mu + base))[l];
  f32x4 vv = ((const f32x4*)(lv + base))[l];
  f32x4 y;
  float s = 0.f, s2 = 0.f;
#pragma unroll
  for (int c = 0; c < 4; ++c) {
    float z = mv[c] + ev[c] * __expf(0.5f * vv[c]);
    z = z > 0.f ? z : (__expf(z) - 1.f);
    float yy = xv[c] + z;
    y[c] = yy;
    s += yy;
    s2 += yy * yy;
  }
#pragma unroll
  for (int d = 1; d < 64; d <<= 1) {
    s += __shfl_xor(s, d, 64);
    s2 += __shfl_xor(s2, d, 64);
  }
  float mean = s * (1.f / 256.f);
  float var = s2 * (1.f / 256.f) - mean * mean;
  float rstd = rsqrtf(var + 1e-5f);
  f32x4 gv = ((const f32x4*)gamma)[l];
  f32x4 bv = ((const f32x4*)beta)[l];
  f32x4 o;
#pragma unroll
  for (int c = 0; c < 4; ++c) o[c] = (y[c] - mean) * rstd * gv[c] + bv[c];
  ((f32x4*)(out + base))[l] = o;
}

// ---------------- launch ----------------
extern "C" void kernel_launch(void* const* d_in, const int* in_sizes, int n_in, void* d_out,
                              int out_size, void* d_ws, size_t ws_size, hipStream_t stream) {
  const float* x = (const float*)d_in[0];
  const float* eps = (const float*)d_in[1];
  const float* Wg = (const float*)d_in[18];
  const float* bg = (const float*)d_in[19];
  const float* gamma = (const float*)d_in[20];
  const float* beta = (const float*)d_in[21];

  char* ws = (char*)d_ws;
  bf16* x16 = (bf16*)(ws);                  // 8 MB
  bf16* h16 = (bf16*)(ws + 8388608);        // 8 MB
  u8* q8 = (u8*)(ws + 25165824);            // 4 MB
  u8* k8 = (u8*)(ws + 29360128);            // 4 MB
  u8* vt8 = (u8*)(ws + 33554432);           // 4 MB (V^T fp8 tile-major)
  bf16* w16 = (bf16*)(ws + 37748736);       // 1 MB (8 x 256x256 bf16)
  float* gpart = (float*)(ws + 38797312);   // 256 KB

  float* out = (float*)d_out;
  float* mu = out + 4194304;
  float* lv = out + 8388608;
  float* pg = out + 12582912;

  WPtrs wp;
  for (int i = 0; i < 8; ++i) wp.p[i] = (const float*)d_in[2 + i];
  cast_all_kernel<<<4608, 256, 0, stream>>>((const f32x4*)x, wp, (ushort4*)x16, (ushort4*)w16);

  GemmIO io1;
  io1.bias[0] = (const float*)d_in[10];
  io1.bias[1] = (const float*)d_in[11];
  io1.bias[2] = (const float*)d_in[12];
  io1.out[0] = q8; io1.out[1] = k8; io1.out[2] = vt8;
  gemm_qkv_kernel<<<dim3(128, 2, 3), 256, 0, stream>>>(x16, w16, io1);
  flash_kernel<<<256, 1024, 0, stream>>>(q8, k8, vt8, h16);

  GemmIO io2;
  io2.bias[0] = (const float*)d_in[13];
  io2.bias[1] = (const float*)d_in[14];
  io2.bias[2] = (const float*)d_in[15];
  io2.out[0] = q8; io2.out[1] = k8; io2.out[2] = vt8;
  gemm_qkv_kernel<<<dim3(128, 2, 3), 256, 0, stream>>>(h16, w16 + 3 * 65536, io2);
  flash_kernel<<<256, 1024, 0, stream>>>(q8, k8, vt8, h16);

  GemmIO io3;
  io3.bias[0] = (const float*)d_in[16];
  io3.bias[1] = (const float*)d_in[17];
  io3.bias[2] = nullptr;
  io3.out[0] = mu; io3.out[1] = lv; io3.out[2] = nullptr;
  gemm_f_kernel<<<dim3(128, 2, 2), 256, 0, stream>>>(h16, w16 + 6 * 65536, io3);

  gate_partial<<<dim3(64, 4), 256, 0, stream>>>(h16, gpart);
  gate_final<<<4, 256, 0, stream>>>(gpart, Wg, bg, pg);
  epilogue_kernel<<<4096, 256, 0, stream>>>(x, eps, mu, lv, gamma, beta, out);
}